// Round 10
// baseline (294.689 us; speedup 1.0000x reference)
//
#include <hip/hip_runtime.h>
#include <hip/hip_bf16.h>

#define T_SEQ 2048
#define DMODEL 2048
#define NB 2
#define NH 16
#define HD 128

typedef __attribute__((ext_vector_type(8))) short short8;
typedef __attribute__((ext_vector_type(4))) float f32x4;
typedef __attribute__((ext_vector_type(16))) float f32x16;
typedef unsigned short ushort_t;

__device__ inline ushort_t f2bf(float f) {
  union { float f; unsigned u; } v; v.f = f;
  unsigned r = v.u + 0x7fffu + ((v.u >> 16) & 1u);
  return (ushort_t)(r >> 16);
}
__device__ inline float bf2f(ushort_t u) {
  union { unsigned u; float f; } v; v.u = ((unsigned)u) << 16;
  return v.f;
}
__device__ inline unsigned pk2(float x, float y) {
  union { __hip_bfloat162 h; unsigned u; } c;
  c.h = __float22bfloat162_rn(float2{x, y});
  return c.u;
}
__device__ inline float fexp2(float x) {
  float r;
  asm("v_exp_f32 %0, %1" : "=v"(r) : "v"(x));
  return r;
}

__device__ inline void gload16(const void* g, void* l) {
  __builtin_amdgcn_global_load_lds(
      (const __attribute__((address_space(1))) unsigned*)g,
      (__attribute__((address_space(3))) unsigned*)l, 16, 0, 0);
}

// ------------- fused fp32 -> bf16 convert (x, w_attn, w_proj) ---------
__global__ void cvt_all(const float* __restrict__ x, const float* __restrict__ wa,
                        const float* __restrict__ wp, ushort_t* __restrict__ xb,
                        ushort_t* __restrict__ wab, ushort_t* __restrict__ wpb,
                        int n8x, int n8a, int n8p) {
  int i = blockIdx.x * blockDim.x + threadIdx.x;
  const float* src; ushort_t* dst; int j;
  if (i < n8x)              { src = x;  dst = xb;  j = i; }
  else if (i < n8x + n8a)   { src = wa; dst = wab; j = i - n8x; }
  else if (i < n8x + n8a + n8p) { src = wp; dst = wpb; j = i - n8x - n8a; }
  else return;
  const float4* s = (const float4*)src + (size_t)j * 2;
  float4 a = s[0], b = s[1];
  short8 o;
  o[0] = (short)f2bf(a.x); o[1] = (short)f2bf(a.y);
  o[2] = (short)f2bf(a.z); o[3] = (short)f2bf(a.w);
  o[4] = (short)f2bf(b.x); o[5] = (short)f2bf(b.y);
  o[6] = (short)f2bf(b.z); o[7] = (short)f2bf(b.w);
  *((short8*)dst + j) = o;
}

// ---------------- cos/sin table: trig[t*128 + i*2]=cos, +1=sin --------
__global__ void trig_init(float* __restrict__ trig) {
  int idx = blockIdx.x * blockDim.x + threadIdx.x;  // T*64
  if (idx >= T_SEQ * 64) return;
  int i = idx & 63, t = idx >> 6;
  float inv = __expf(-(float)i * (9.210340371976184f / 64.0f));
  float f = (float)t * inv;
  trig[idx * 2]     = cosf(f);
  trig[idx * 2 + 1] = sinf(f);
}

// ---------------- V transpose: [B][H][T][128] -> [B][H][128][T] -------
__global__ __launch_bounds__(256)
void v_transpose(const ushort_t* __restrict__ v, ushort_t* __restrict__ vt) {
  __shared__ __align__(16) ushort_t L[64][136];
  int bh = blockIdx.y;
  int t0 = blockIdx.x * 64;
  int tid = threadIdx.x;
  int row = tid >> 2, c0 = (tid & 3) * 32;
  const ushort_t* src = v + ((size_t)bh * T_SEQ + t0 + row) * HD + c0;
#pragma unroll
  for (int j = 0; j < 4; ++j)
    *(short8*)&L[row][c0 + j * 8] = *(const short8*)(src + j * 8);
  __syncthreads();
  int d = tid >> 1, tc = (tid & 1) * 32;
  union { ushort_t u[32]; short8 v8[4]; } buf;
#pragma unroll
  for (int j = 0; j < 32; ++j) buf.u[j] = L[tc + j][d];
  ushort_t* dst = vt + ((size_t)bh * HD + d) * T_SEQ + t0 + tc;
#pragma unroll
  for (int j = 0; j < 4; ++j) *(short8*)(dst + j * 8) = buf.v8[j];
}

// ===== 128x128 BK=32 double-buffered GEMM (m97 sweet-spot tile) =======
// C = A[M][K] * Bt[N][K]^T. 256 thr = 4 waves (2M x 2N), per-wave 64x64.
// Per K-tile: {stage(kt+1 -> buf^1): 4 gload16 | 8 ds_read_b128 | 16 MFMA
// (setprio) | __syncthreads}. ONE barrier/K-tile; 32KB LDS + ~120 combined
// regs -> 4 blocks/CU co-resident hide the drain (m114/m103: 128tile=912TF).
// LDS: row pairs packed as 128B super-rows of 8 x 16B slots; row r chunk g
// at slot s = (((r&1)<<2)|g) ^ ((r>>1)&7)  (conflict-free read, R9-verified:
// conflicts 12.58M -> 0). Stage: linear gload_lds dest, decode on source.
template <int EPI>
__global__ __launch_bounds__(256, 4)
void gemm_s(const ushort_t* __restrict__ A, const ushort_t* __restrict__ Bt,
            float* __restrict__ C, ushort_t* __restrict__ q_t,
            ushort_t* __restrict__ k_t, ushort_t* __restrict__ v_t,
            const float* __restrict__ trig, int M, int N, int K) {
  __shared__ __align__(16) ushort_t sA[2][128 * 32];  // 2 x 8KB
  __shared__ __align__(16) ushort_t sB[2][128 * 32];  // 2 x 8KB
  int tid = threadIdx.x, lane = tid & 63, w = tid >> 6;
  int wm = w >> 1, wn = w & 1;
  int li = lane & 15, lg = lane >> 4;
  int tile_m = blockIdx.y * 128, tile_n = blockIdx.x * 128;
  const ushort_t* Ag = A + (size_t)tile_m * K;
  const ushort_t* Bg = Bt + (size_t)tile_n * K;

  // stage decode: lane's linear LDS slot -> global (row, chunk)
  int Rl = tid >> 3;           // superrow within instruction (0..31)
  int sl = tid & 7;            // slot
  int tdec = sl ^ (Rl & 7);    // (i*32 multiple of 8 -> i drops out)
  int prow = (tdec >> 2) & 1, gch = tdec & 3;

  auto stage = [&](int kt, int buf) {
#pragma unroll
    for (int i = 0; i < 2; ++i) {  // A: 2 insts x 32 superrows (64 rows each)
      int grow = (i * 32 + Rl) * 2 + prow;
      gload16(Ag + (size_t)grow * K + kt * 32 + gch * 8,
              &sA[buf][i * 2048 + tid * 8]);
    }
#pragma unroll
    for (int i = 0; i < 2; ++i) {  // B: 2 insts
      int grow = (i * 32 + Rl) * 2 + prow;
      gload16(Bg + (size_t)grow * K + kt * 32 + gch * 8,
              &sB[buf][i * 2048 + tid * 8]);
    }
  };

  // read addressing: row r, global chunk lg -> ushort offset
  auto rdoff = [&](int r) {
    int R = r >> 1;
    int s = (((r & 1) << 2) | lg) ^ (R & 7);
    return R * 64 + s * 8;
  };

  f32x4 acc[4][4] = {};
  const int NT = K / 32;

  stage(0, 0);
  __syncthreads();

  for (int kt = 0; kt < NT; ++kt) {
    int cur = kt & 1;
    if (kt + 1 < NT) stage(kt + 1, cur ^ 1);
    short8 af[4], bf[4];
#pragma unroll
    for (int mi = 0; mi < 4; ++mi)
      af[mi] = *(const short8*)&sA[cur][rdoff(wm * 64 + mi * 16 + li)];
#pragma unroll
    for (int ni = 0; ni < 4; ++ni)
      bf[ni] = *(const short8*)&sB[cur][rdoff(wn * 64 + ni * 16 + li)];
    __builtin_amdgcn_s_setprio(1);
#pragma unroll
    for (int mi = 0; mi < 4; ++mi)
#pragma unroll
      for (int ni = 0; ni < 4; ++ni)
        acc[mi][ni] = __builtin_amdgcn_mfma_f32_16x16x32_bf16(af[mi], bf[ni], acc[mi][ni], 0, 0, 0);
    __builtin_amdgcn_s_setprio(0);
    __syncthreads();   // drains vmcnt(0)+lgkmcnt(0): buf^1 writes landed
  }

  if (EPI == 0) {
#pragma unroll
    for (int mi = 0; mi < 4; ++mi) {
      int trow = tile_m + wm * 64 + mi * 16 + lg * 4;
#pragma unroll
      for (int ni = 0; ni < 4; ++ni) {
        int col = tile_n + wn * 64 + ni * 16 + li;
#pragma unroll
        for (int r = 0; r < 4; ++r)
          C[(size_t)(trow + r) * N + col] = acc[mi][ni][r];
      }
    }
  } else {
    int sec = tile_n >> 11;          // block-uniform (128-wide tile, one head)
    int bq  = tile_m >> 11;
    int t0  = tile_m & 2047;
    int h   = (tile_n & 2047) >> 7;
#pragma unroll
    for (int mi = 0; mi < 4; ++mi) {
      int tl = wm * 64 + mi * 16 + lg * 4;
#pragma unroll
      for (int ni = 0; ni < 4; ++ni) {
        int d = wn * 64 + ni * 16 + li;
        if (sec < 2) {
          ushort_t* base = ((sec == 0) ? q_t : k_t) + ((size_t)(bq * NH + h)) * T_SEQ * HD;
          int fi2 = (d >> 1) * 2;
#pragma unroll
          for (int r = 0; r < 4; ++r) {
            int t = t0 + tl + r;
            float val = acc[mi][ni][r];
            float par = __shfl_xor(val, 1);
            const float* tp = trig + t * 128 + fi2;
            float c = tp[0], s = tp[1];
            float outv = (li & 1) ? (par * s + val * c) : (val * c - par * s);
            base[(size_t)t * HD + d] = f2bf(outv);
          }
        } else {
          ushort_t* base = v_t + ((size_t)(bq * NH + h)) * T_SEQ * HD;
#pragma unroll
          for (int r = 0; r < 4; ++r)
            base[(size_t)(t0 + tl + r) * HD + d] = f2bf(acc[mi][ni][r]);
        }
      }
    }
  }
}

// ---------------- Flash attention (causal), swapped-QK 32x32 ----------
__global__ __launch_bounds__(256, 2)
void flash_attn(const ushort_t* __restrict__ Q, const ushort_t* __restrict__ Kg,
                const ushort_t* __restrict__ Vt, ushort_t* __restrict__ Y) {
  __shared__ __align__(16) ushort_t ldsK[2 * 64 * 128];   // 32KB, 2 buf
  __shared__ __align__(16) ushort_t ldsV[2 * 128 * 64];   // 32KB, 2 buf
  int tid = threadIdx.x, lane = tid & 63, w = tid >> 6;
  int hi = lane >> 5, l31 = lane & 31;
  int qi = (blockIdx.y & 16) ? (15 - (int)blockIdx.x) : (int)blockIdx.x;
  int bh = blockIdx.y;
  int b = bh >> 4, h = bh & 15;
  int q0 = qi * 128;
  const ushort_t* Qp = Q + (size_t)bh * T_SEQ * HD;
  const ushort_t* Kp = Kg + (size_t)bh * T_SEQ * HD;
  const ushort_t* Vp = Vt + (size_t)bh * HD * T_SEQ;

  int qg = q0 + w * 32 + l31;
  int qmaxw = q0 + w * 32 + 31;

  auto stage = [&](int kv0, int bsel) {
    ushort_t* Kb = ldsK + bsel * 8192;
    ushort_t* Vb = ldsV + bsel * 8192;
#pragma unroll
    for (int p = 0; p < 4; ++p) {
      int c = p * 256 + w * 64 + lane;
      {
        int row = c >> 4, cc = c & 15;
        int sc = cc ^ (row & 15);
        gload16(Kp + (size_t)(kv0 + row) * HD + sc * 8, Kb + (p * 256 + w * 64) * 8);
      }
      {
        int d = c >> 3, cc = c & 7;
        int sc = cc ^ (d & 7);
        gload16(Vp + (size_t)d * T_SEQ + kv0 + sc * 8, Vb + (p * 256 + w * 64) * 8);
      }
    }
  };

  short8 qf[8];
#pragma unroll
  for (int ds = 0; ds < 8; ++ds)
    qf[ds] = *(const short8*)(Qp + (size_t)qg * HD + ds * 16 + hi * 8);

  f32x16 o[4] = {};
  float mu = -1e30f, l = 0.f;
  const float SIG = 0.12751879523209784f;  // (1/sqrt(128)) * log2(e)

  int nkt = 2 * qi + 2;
  stage(0, 0);
  __syncthreads();
  int cur = 0;
  for (int kt = 0; kt < nkt; ++kt) {
    int kv0 = kt * 64;
    if (kt + 1 < nkt) stage((kt + 1) * 64, cur ^ 1);
    if (kv0 <= qmaxw) {
      const ushort_t* Kb = ldsK + cur * 8192;
      const ushort_t* Vb = ldsV + cur * 8192;
      f32x16 sa = {}, sb = {};
      __builtin_amdgcn_s_setprio(1);
#pragma unroll
      for (int ds = 0; ds < 8; ++ds) {
        int cc = ds * 2 + hi;
        short8 k0 = *(const short8*)&Kb[l31 * 128 + ((cc ^ (l31 & 15)) * 8)];
        short8 k1 = *(const short8*)&Kb[(32 + l31) * 128 + ((cc ^ (l31 & 15)) * 8)];
        sa = __builtin_amdgcn_mfma_f32_32x32x16_bf16(k0, qf[ds], sa, 0, 0, 0);
        sb = __builtin_amdgcn_mfma_f32_32x32x16_bf16(k1, qf[ds], sb, 0, 0, 0);
      }
      __builtin_amdgcn_s_setprio(0);
      float p[32];
#pragma unroll
      for (int r = 0; r < 16; ++r) { p[r] = sa[r] * SIG; p[16 + r] = sb[r] * SIG; }
      if (kv0 + 63 > q0 + w * 32) {
#pragma unroll
        for (int r = 0; r < 16; ++r) {
          int loc = (r & 3) + 8 * (r >> 2) + 4 * hi;
          if (kv0 + loc > qg)      p[r]      = -3e38f;
          if (kv0 + 32 + loc > qg) p[16 + r] = -3e38f;
        }
      }
      float tm[16];
#pragma unroll
      for (int i = 0; i < 16; ++i) tm[i] = fmaxf(p[i], p[i + 16]);
#pragma unroll
      for (int st = 8; st >= 1; st >>= 1)
#pragma unroll
        for (int i = 0; i < 8; ++i)
          if (i < st) tm[i] = fmaxf(tm[i], tm[i + st]);
      float pmax = fmaxf(tm[0], __shfl_xor(tm[0], 32));
      bool resc = !__all(pmax <= mu + 11.0f);
      if (resc) {
        float munew = fmaxf(mu, pmax);
        float alpha = fexp2(mu - munew);
        mu = munew;
        l *= alpha;
#pragma unroll
        for (int dsub = 0; dsub < 4; ++dsub)
#pragma unroll
          for (int r = 0; r < 16; ++r) o[dsub][r] *= alpha;
      }
#pragma unroll
      for (int i = 0; i < 32; ++i) p[i] = fexp2(p[i] - mu);
      float ts[16];
#pragma unroll
      for (int i = 0; i < 16; ++i) ts[i] = p[i] + p[i + 16];
#pragma unroll
      for (int st = 8; st >= 1; st >>= 1)
#pragma unroll
        for (int i = 0; i < 8; ++i)
          if (i < st) ts[i] += ts[i + st];
      l += ts[0] + __shfl_xor(ts[0], 32);
      __builtin_amdgcn_s_setprio(1);
#pragma unroll
      for (int s = 0; s < 4; ++s) {
        int rb = (s >> 1) * 16 + (s & 1) * 8;
        unsigned a0 = pk2(p[rb + 0], p[rb + 1]);
        unsigned a1 = pk2(p[rb + 2], p[rb + 3]);
        unsigned a2 = pk2(p[rb + 4], p[rb + 5]);
        unsigned a3 = pk2(p[rb + 6], p[rb + 7]);
        unsigned sa0 = (unsigned)__shfl_xor((int)a0, 32);
        unsigned sa1 = (unsigned)__shfl_xor((int)a1, 32);
        unsigned sa2 = (unsigned)__shfl_xor((int)a2, 32);
        unsigned sa3 = (unsigned)__shfl_xor((int)a3, 32);
        union { unsigned u[4]; short8 s8; } pf;
        pf.u[0] = hi ? sa2 : a0;
        pf.u[1] = hi ? sa3 : a1;
        pf.u[2] = hi ? a2 : sa0;
        pf.u[3] = hi ? a3 : sa1;
#pragma unroll
        for (int dsub = 0; dsub < 4; ++dsub) {
          int row = dsub * 32 + l31;
          short8 vf = *(const short8*)&Vb[row * 64 + (((2 * s + hi) ^ (row & 7)) * 8)];
          o[dsub] = __builtin_amdgcn_mfma_f32_32x32x16_bf16(vf, pf.s8, o[dsub], 0, 0, 0);
        }
      }
      __builtin_amdgcn_s_setprio(0);
    }
    __syncthreads();
    cur ^= 1;
  }
  float invl = 1.f / l;
#pragma unroll
  for (int dsub = 0; dsub < 4; ++dsub)
#pragma unroll
    for (int r = 0; r < 16; ++r) o[dsub][r] *= invl;
#pragma unroll
  for (int dsub = 0; dsub < 4; ++dsub)
#pragma unroll
    for (int r = 0; r < 16; r += 2) {
      int d0 = dsub * 32 + (r & 3) + 8 * (r >> 2) + 4 * hi;
      unsigned u = pk2(o[dsub][r], o[dsub][r + 1]);
      *(unsigned*)&ldsK[w * 4096 + l31 * 128 + (((d0 >> 3) ^ (l31 & 15)) * 8) + (d0 & 7)] = u;
    }
  __syncthreads();
#pragma unroll
  for (int rep = 0; rep < 8; ++rep) {
    int idx = rep * 256 + tid;
    int qg2 = idx >> 4, c = idx & 15;
    int wv2 = qg2 >> 5, ql = qg2 & 31;
    short8 val = *(const short8*)&ldsK[wv2 * 4096 + ql * 128 + ((c ^ (ql & 15)) * 8)];
    *(short8*)(Y + ((size_t)(b * T_SEQ + q0 + qg2)) * DMODEL + h * HD + c * 8) = val;
  }
}

extern "C" void kernel_launch(void* const* d_in, const int* in_sizes, int n_in,
                              void* d_out, int out_size, void* d_ws, size_t ws_size,
                              hipStream_t stream) {
  const float* x      = (const float*)d_in[0];
  const float* w_attn = (const float*)d_in[1];
  const float* w_proj = (const float*)d_in[2];
  float* out = (float*)d_out;

  char* ws = (char*)d_ws;
  size_t off = 0;
  auto alloc = [&](size_t bytes) -> void* {
    void* p = ws + off;
    off = (off + bytes + 255) & ~(size_t)255;
    return p;
  };
  const size_t MT = (size_t)NB * T_SEQ;          // 4096
  ushort_t* xb   = (ushort_t*)alloc(MT * DMODEL * 2);
  ushort_t* wab  = (ushort_t*)alloc((size_t)3 * DMODEL * DMODEL * 2);
  ushort_t* wpb  = (ushort_t*)alloc((size_t)DMODEL * DMODEL * 2);
  ushort_t* q_t  = (ushort_t*)alloc(MT * DMODEL * 2);
  ushort_t* k_t  = (ushort_t*)alloc(MT * DMODEL * 2);
  ushort_t* v_t  = (ushort_t*)alloc(MT * DMODEL * 2);
  ushort_t* vtb  = (ushort_t*)alloc(MT * DMODEL * 2);
  ushort_t* yb   = (ushort_t*)alloc(MT * DMODEL * 2);
  float*    trig = (float*)alloc((size_t)T_SEQ * 64 * 2 * 4);
  (void)ws_size; (void)n_in; (void)in_sizes; (void)out_size;

  {  // one fused convert launch
    int n8x = (int)(MT * DMODEL / 8);
    int n8a = (int)((size_t)3 * DMODEL * DMODEL / 8);
    int n8p = (int)((size_t)DMODEL * DMODEL / 8);
    int tot = n8x + n8a + n8p;
    hipLaunchKernelGGL(cvt_all, dim3((tot + 255) / 256), dim3(256), 0, stream,
                       x, w_attn, w_proj, xb, wab, wpb, n8x, n8a, n8p);
  }
  hipLaunchKernelGGL(trig_init, dim3(T_SEQ * 64 / 256), dim3(256), 0, stream, trig);

  // QKV projection (128x128 m97 tile), rope fused q/k, plain v scatter
  hipLaunchKernelGGL((gemm_s<1>), dim3(3 * DMODEL / 128, MT / 128), dim3(256), 0, stream,
                     xb, wab, (float*)nullptr, q_t, k_t, v_t, trig,
                     (int)MT, 3 * DMODEL, DMODEL);

  hipLaunchKernelGGL(v_transpose, dim3(T_SEQ / 64, NB * NH), dim3(256), 0, stream, v_t, vtb);

  hipLaunchKernelGGL(flash_attn, dim3(T_SEQ / 128, NB * NH), dim3(256), 0, stream,
                     q_t, k_t, vtb, yb);

  // output projection
  hipLaunchKernelGGL((gemm_s<0>), dim3(DMODEL / 128, MT / 128), dim3(256), 0, stream,
                     yb, wpb, out, (ushort_t*)nullptr, (ushort_t*)nullptr, (ushort_t*)nullptr,
                     (const float*)nullptr, (int)MT, DMODEL, DMODEL);
}

// Round 11
// 279.155 us; speedup vs baseline: 1.0556x; 1.0556x over previous
//
#include <hip/hip_runtime.h>
#include <hip/hip_bf16.h>

#define T_SEQ 2048
#define DMODEL 2048
#define NB 2
#define NH 16
#define HD 128

typedef __attribute__((ext_vector_type(8))) short short8;
typedef __attribute__((ext_vector_type(4))) float f32x4;
typedef __attribute__((ext_vector_type(16))) float f32x16;
typedef unsigned short ushort_t;

__device__ inline ushort_t f2bf(float f) {
  union { float f; unsigned u; } v; v.f = f;
  unsigned r = v.u + 0x7fffu + ((v.u >> 16) & 1u);
  return (ushort_t)(r >> 16);
}
__device__ inline float bf2f(ushort_t u) {
  union { unsigned u; float f; } v; v.u = ((unsigned)u) << 16;
  return v.f;
}
__device__ inline unsigned pk2(float x, float y) {
  union { __hip_bfloat162 h; unsigned u; } c;
  c.h = __float22bfloat162_rn(float2{x, y});
  return c.u;
}
__device__ inline float fexp2(float x) {
  float r;
  asm("v_exp_f32 %0, %1" : "=v"(r) : "v"(x));
  return r;
}

__device__ inline void gload16(const void* g, void* l) {
  __builtin_amdgcn_global_load_lds(
      (const __attribute__((address_space(1))) unsigned*)g,
      (__attribute__((address_space(3))) unsigned*)l, 16, 0, 0);
}

// ------------- fused fp32 -> bf16 convert (x, w_attn, w_proj) ---------
__global__ void cvt_all(const float* __restrict__ x, const float* __restrict__ wa,
                        const float* __restrict__ wp, ushort_t* __restrict__ xb,
                        ushort_t* __restrict__ wab, ushort_t* __restrict__ wpb,
                        int n8x, int n8a, int n8p) {
  int i = blockIdx.x * blockDim.x + threadIdx.x;
  const float* src; ushort_t* dst; int j;
  if (i < n8x)              { src = x;  dst = xb;  j = i; }
  else if (i < n8x + n8a)   { src = wa; dst = wab; j = i - n8x; }
  else if (i < n8x + n8a + n8p) { src = wp; dst = wpb; j = i - n8x - n8a; }
  else return;
  const float4* s = (const float4*)src + (size_t)j * 2;
  float4 a = s[0], b = s[1];
  short8 o;
  o[0] = (short)f2bf(a.x); o[1] = (short)f2bf(a.y);
  o[2] = (short)f2bf(a.z); o[3] = (short)f2bf(a.w);
  o[4] = (short)f2bf(b.x); o[5] = (short)f2bf(b.y);
  o[6] = (short)f2bf(b.z); o[7] = (short)f2bf(b.w);
  *((short8*)dst + j) = o;
}

// ---------------- cos/sin table: trig[t*128 + i*2]=cos, +1=sin --------
__global__ void trig_init(float* __restrict__ trig) {
  int idx = blockIdx.x * blockDim.x + threadIdx.x;  // T*64
  if (idx >= T_SEQ * 64) return;
  int i = idx & 63, t = idx >> 6;
  float inv = __expf(-(float)i * (9.210340371976184f / 64.0f));
  float f = (float)t * inv;
  trig[idx * 2]     = cosf(f);
  trig[idx * 2 + 1] = sinf(f);
}

// ===== 256x128 BK=32 double-buffered GEMM, m97 regime, 0-conflict =====
// (R9-verified config: QKV 134us, conflicts 0, occupancy ~33%.)
// C = A[M][K] * Bt[N][K]^T. 512 thr = 8 waves (4M x 2N), per-wave 64x64.
// Per K-tile: {stage(kt+1 -> buf^1): 3 gload16 | 8 ds_read_b128 | 16 MFMA
// (setprio) | __syncthreads}. ONE barrier/K-tile; 2 blocks/CU hide drain.
// LDS: row pairs packed as 128B super-rows of 8 x 16B slots; row r chunk g
// at slot s = (((r&1)<<2)|g) ^ ((r>>1)&7); linear gload dest, decode on src.
// EPI=1 epilogue: q,k rope-fused scatter; v LDS-transposed -> vt[d][T].
template <int EPI>
__global__ __launch_bounds__(512, 4)
void gemm_s(const ushort_t* __restrict__ A, const ushort_t* __restrict__ Bt,
            float* __restrict__ C, ushort_t* __restrict__ q_t,
            ushort_t* __restrict__ k_t, ushort_t* __restrict__ v_t,
            const float* __restrict__ trig, int M, int N, int K) {
  __shared__ __align__(16) ushort_t sA[2][256 * 32];  // 2 x 16KB
  __shared__ __align__(16) ushort_t sB[2][128 * 32];  // 2 x 8KB
  int tid = threadIdx.x, lane = tid & 63, w = tid >> 6;
  int wm = w >> 1, wn = w & 1;
  int li = lane & 15, lg = lane >> 4;
  int tile_m = blockIdx.y * 256, tile_n = blockIdx.x * 128;
  const ushort_t* Ag = A + (size_t)tile_m * K;
  const ushort_t* Bg = Bt + (size_t)tile_n * K;

  // stage decode: lane's linear LDS slot -> global (row, chunk)
  int Rl = tid >> 3;           // superrow within instruction span
  int sl = tid & 7;            // slot
  int tdec = sl ^ (Rl & 7);
  int prow = (tdec >> 2) & 1, gch = tdec & 3;

  auto stage = [&](int kt, int buf) {
#pragma unroll
    for (int i = 0; i < 2; ++i) {  // A: 2 instrs x 64 superrows (128 rows)
      int grow = (i * 64 + Rl) * 2 + prow;
      gload16(Ag + (size_t)grow * K + kt * 32 + gch * 8,
              &sA[buf][i * 4096 + tid * 8]);
    }
    {                              // B: 1 instr x 64 superrows (128 rows)
      int grow = Rl * 2 + prow;
      gload16(Bg + (size_t)grow * K + kt * 32 + gch * 8,
              &sB[buf][tid * 8]);
    }
  };

  // read addressing: row r, global chunk lg -> element offset
  auto rdoff = [&](int r) {
    int R = r >> 1;
    int s = (((r & 1) << 2) | lg) ^ (R & 7);
    return R * 64 + s * 8;
  };

  f32x4 acc[4][4] = {};
  const int NT = K / 32;

  stage(0, 0);
  __syncthreads();

  for (int kt = 0; kt < NT; ++kt) {
    int cur = kt & 1;
    if (kt + 1 < NT) stage(kt + 1, cur ^ 1);
    short8 af[4], bf[4];
#pragma unroll
    for (int mi = 0; mi < 4; ++mi)
      af[mi] = *(const short8*)&sA[cur][rdoff(wm * 64 + mi * 16 + li)];
#pragma unroll
    for (int ni = 0; ni < 4; ++ni)
      bf[ni] = *(const short8*)&sB[cur][rdoff(wn * 64 + ni * 16 + li)];
    __builtin_amdgcn_s_setprio(1);
#pragma unroll
    for (int mi = 0; mi < 4; ++mi)
#pragma unroll
      for (int ni = 0; ni < 4; ++ni)
        acc[mi][ni] = __builtin_amdgcn_mfma_f32_16x16x32_bf16(af[mi], bf[ni], acc[mi][ni], 0, 0, 0);
    __builtin_amdgcn_s_setprio(0);
    __syncthreads();   // drains vmcnt(0)+lgkmcnt(0): buf^1 writes landed
  }

  if (EPI == 0) {
#pragma unroll
    for (int mi = 0; mi < 4; ++mi) {
      int trow = tile_m + wm * 64 + mi * 16 + lg * 4;
#pragma unroll
      for (int ni = 0; ni < 4; ++ni) {
        int col = tile_n + wn * 64 + ni * 16 + li;
#pragma unroll
        for (int r = 0; r < 4; ++r)
          C[(size_t)(trow + r) * N + col] = acc[mi][ni][r];
      }
    }
  } else {
    int sec = tile_n >> 11;          // block-uniform (128-wide tile, one head)
    int bq  = tile_m >> 11;
    int t0  = tile_m & 2047;
    int h   = (tile_n & 2047) >> 7;
    if (sec < 2) {
      ushort_t* base = ((sec == 0) ? q_t : k_t) + ((size_t)(bq * NH + h)) * T_SEQ * HD;
#pragma unroll
      for (int mi = 0; mi < 4; ++mi) {
        int tl = wm * 64 + mi * 16 + lg * 4;
#pragma unroll
        for (int ni = 0; ni < 4; ++ni) {
          int d = wn * 64 + ni * 16 + li;
          int fi2 = (d >> 1) * 2;
#pragma unroll
          for (int r = 0; r < 4; ++r) {
            int t = t0 + tl + r;
            float val = acc[mi][ni][r];
            float par = __shfl_xor(val, 1);
            const float* tp = trig + t * 128 + fi2;
            float c = tp[0], s = tp[1];
            float outv = (li & 1) ? (par * s + val * c) : (val * c - par * s);
            base[(size_t)t * HD + d] = f2bf(outv);
          }
        }
      }
    } else {
      // V: LDS-transpose the 256(t) x 128(d) tile in 4 chunks of 64 t-rows,
      // store vt[bh][d][T] coalesced. Reuses sA as padded [128][72] buffer.
      ushort_t* vbase = v_t + ((size_t)(bq * NH + h)) * HD * T_SEQ;
      ushort_t* L = (ushort_t*)sA;
      for (int c = 0; c < 4; ++c) {
        if (wm == c) {
#pragma unroll
          for (int mi = 0; mi < 4; ++mi) {
            int tl = mi * 16 + lg * 4;
#pragma unroll
            for (int ni = 0; ni < 4; ++ni) {
              int d = wn * 64 + ni * 16 + li;
#pragma unroll
              for (int r = 0; r < 4; ++r)
                L[d * 72 + tl + r] = f2bf(acc[mi][ni][r]);
            }
          }
        }
        __syncthreads();
#pragma unroll
        for (int j = 0; j < 2; ++j) {
          int idx = j * 512 + tid;
          int d = idx >> 3, tg = (idx & 7) * 8;
          short8 val = *(const short8*)&L[d * 72 + tg];
          *(short8*)(vbase + (size_t)d * T_SEQ + t0 + c * 64 + tg) = val;
        }
        __syncthreads();
      }
    }
  }
}

// ---------------- Flash attention (causal), swapped-QK 32x32 ----------
__global__ __launch_bounds__(256, 2)
void flash_attn(const ushort_t* __restrict__ Q, const ushort_t* __restrict__ Kg,
                const ushort_t* __restrict__ Vt, ushort_t* __restrict__ Y) {
  __shared__ __align__(16) ushort_t ldsK[2 * 64 * 128];   // 32KB, 2 buf
  __shared__ __align__(16) ushort_t ldsV[2 * 128 * 64];   // 32KB, 2 buf
  int tid = threadIdx.x, lane = tid & 63, w = tid >> 6;
  int hi = lane >> 5, l31 = lane & 31;
  int qi = (blockIdx.y & 16) ? (15 - (int)blockIdx.x) : (int)blockIdx.x;
  int bh = blockIdx.y;
  int b = bh >> 4, h = bh & 15;
  int q0 = qi * 128;
  const ushort_t* Qp = Q + (size_t)bh * T_SEQ * HD;
  const ushort_t* Kp = Kg + (size_t)bh * T_SEQ * HD;
  const ushort_t* Vp = Vt + (size_t)bh * HD * T_SEQ;

  int qg = q0 + w * 32 + l31;
  int qmaxw = q0 + w * 32 + 31;

  auto stage = [&](int kv0, int bsel) {
    ushort_t* Kb = ldsK + bsel * 8192;
    ushort_t* Vb = ldsV + bsel * 8192;
#pragma unroll
    for (int p = 0; p < 4; ++p) {
      int c = p * 256 + w * 64 + lane;
      {
        int row = c >> 4, cc = c & 15;
        int sc = cc ^ (row & 15);
        gload16(Kp + (size_t)(kv0 + row) * HD + sc * 8, Kb + (p * 256 + w * 64) * 8);
      }
      {
        int d = c >> 3, cc = c & 7;
        int sc = cc ^ (d & 7);
        gload16(Vp + (size_t)d * T_SEQ + kv0 + sc * 8, Vb + (p * 256 + w * 64) * 8);
      }
    }
  };

  short8 qf[8];
#pragma unroll
  for (int ds = 0; ds < 8; ++ds)
    qf[ds] = *(const short8*)(Qp + (size_t)qg * HD + ds * 16 + hi * 8);

  f32x16 o[4] = {};
  float mu = -1e30f, l = 0.f;
  const float SIG = 0.12751879523209784f;  // (1/sqrt(128)) * log2(e)

  int nkt = 2 * qi + 2;
  stage(0, 0);
  __syncthreads();
  int cur = 0;
  for (int kt = 0; kt < nkt; ++kt) {
    int kv0 = kt * 64;
    if (kt + 1 < nkt) stage((kt + 1) * 64, cur ^ 1);
    if (kv0 <= qmaxw) {
      const ushort_t* Kb = ldsK + cur * 8192;
      const ushort_t* Vb = ldsV + cur * 8192;
      f32x16 sa = {}, sb = {};
      __builtin_amdgcn_s_setprio(1);
#pragma unroll
      for (int ds = 0; ds < 8; ++ds) {
        int cc = ds * 2 + hi;
        short8 k0 = *(const short8*)&Kb[l31 * 128 + ((cc ^ (l31 & 15)) * 8)];
        short8 k1 = *(const short8*)&Kb[(32 + l31) * 128 + ((cc ^ (l31 & 15)) * 8)];
        sa = __builtin_amdgcn_mfma_f32_32x32x16_bf16(k0, qf[ds], sa, 0, 0, 0);
        sb = __builtin_amdgcn_mfma_f32_32x32x16_bf16(k1, qf[ds], sb, 0, 0, 0);
      }
      __builtin_amdgcn_s_setprio(0);
      float p[32];
#pragma unroll
      for (int r = 0; r < 16; ++r) { p[r] = sa[r] * SIG; p[16 + r] = sb[r] * SIG; }
      if (kv0 + 63 > q0 + w * 32) {
#pragma unroll
        for (int r = 0; r < 16; ++r) {
          int loc = (r & 3) + 8 * (r >> 2) + 4 * hi;
          if (kv0 + loc > qg)      p[r]      = -3e38f;
          if (kv0 + 32 + loc > qg) p[16 + r] = -3e38f;
        }
      }
      float tm[16];
#pragma unroll
      for (int i = 0; i < 16; ++i) tm[i] = fmaxf(p[i], p[i + 16]);
#pragma unroll
      for (int st = 8; st >= 1; st >>= 1)
#pragma unroll
        for (int i = 0; i < 8; ++i)
          if (i < st) tm[i] = fmaxf(tm[i], tm[i + st]);
      float pmax = fmaxf(tm[0], __shfl_xor(tm[0], 32));
      bool resc = !__all(pmax <= mu + 11.0f);
      if (resc) {
        float munew = fmaxf(mu, pmax);
        float alpha = fexp2(mu - munew);
        mu = munew;
        l *= alpha;
#pragma unroll
        for (int dsub = 0; dsub < 4; ++dsub)
#pragma unroll
          for (int r = 0; r < 16; ++r) o[dsub][r] *= alpha;
      }
#pragma unroll
      for (int i = 0; i < 32; ++i) p[i] = fexp2(p[i] - mu);
      float ts[16];
#pragma unroll
      for (int i = 0; i < 16; ++i) ts[i] = p[i] + p[i + 16];
#pragma unroll
      for (int st = 8; st >= 1; st >>= 1)
#pragma unroll
        for (int i = 0; i < 8; ++i)
          if (i < st) ts[i] += ts[i + st];
      l += ts[0] + __shfl_xor(ts[0], 32);
      __builtin_amdgcn_s_setprio(1);
#pragma unroll
      for (int s = 0; s < 4; ++s) {
        int rb = (s >> 1) * 16 + (s & 1) * 8;
        unsigned a0 = pk2(p[rb + 0], p[rb + 1]);
        unsigned a1 = pk2(p[rb + 2], p[rb + 3]);
        unsigned a2 = pk2(p[rb + 4], p[rb + 5]);
        unsigned a3 = pk2(p[rb + 6], p[rb + 7]);
        unsigned sa0 = (unsigned)__shfl_xor((int)a0, 32);
        unsigned sa1 = (unsigned)__shfl_xor((int)a1, 32);
        unsigned sa2 = (unsigned)__shfl_xor((int)a2, 32);
        unsigned sa3 = (unsigned)__shfl_xor((int)a3, 32);
        union { unsigned u[4]; short8 s8; } pf;
        pf.u[0] = hi ? sa2 : a0;
        pf.u[1] = hi ? sa3 : a1;
        pf.u[2] = hi ? a2 : sa0;
        pf.u[3] = hi ? a3 : sa1;
#pragma unroll
        for (int dsub = 0; dsub < 4; ++dsub) {
          int row = dsub * 32 + l31;
          short8 vf = *(const short8*)&Vb[row * 64 + (((2 * s + hi) ^ (row & 7)) * 8)];
          o[dsub] = __builtin_amdgcn_mfma_f32_32x32x16_bf16(vf, pf.s8, o[dsub], 0, 0, 0);
        }
      }
      __builtin_amdgcn_s_setprio(0);
    }
    __syncthreads();
    cur ^= 1;
  }
  float invl = 1.f / l;
#pragma unroll
  for (int dsub = 0; dsub < 4; ++dsub)
#pragma unroll
    for (int r = 0; r < 16; ++r) o[dsub][r] *= invl;
#pragma unroll
  for (int dsub = 0; dsub < 4; ++dsub)
#pragma unroll
    for (int r = 0; r < 16; r += 2) {
      int d0 = dsub * 32 + (r & 3) + 8 * (r >> 2) + 4 * hi;
      unsigned u = pk2(o[dsub][r], o[dsub][r + 1]);
      *(unsigned*)&ldsK[w * 4096 + l31 * 128 + (((d0 >> 3) ^ (l31 & 15)) * 8) + (d0 & 7)] = u;
    }
  __syncthreads();
#pragma unroll
  for (int rep = 0; rep < 8; ++rep) {
    int idx = rep * 256 + tid;
    int qg2 = idx >> 4, c = idx & 15;
    int wv2 = qg2 >> 5, ql = qg2 & 31;
    short8 val = *(const short8*)&ldsK[wv2 * 4096 + ql * 128 + ((c ^ (ql & 15)) * 8)];
    *(short8*)(Y + ((size_t)(b * T_SEQ + q0 + qg2)) * DMODEL + h * HD + c * 8) = val;
  }
}

extern "C" void kernel_launch(void* const* d_in, const int* in_sizes, int n_in,
                              void* d_out, int out_size, void* d_ws, size_t ws_size,
                              hipStream_t stream) {
  const float* x      = (const float*)d_in[0];
  const float* w_attn = (const float*)d_in[1];
  const float* w_proj = (const float*)d_in[2];
  float* out = (float*)d_out;

  char* ws = (char*)d_ws;
  size_t off = 0;
  auto alloc = [&](size_t bytes) -> void* {
    void* p = ws + off;
    off = (off + bytes + 255) & ~(size_t)255;
    return p;
  };
  const size_t MT = (size_t)NB * T_SEQ;          // 4096
  ushort_t* xb   = (ushort_t*)alloc(MT * DMODEL * 2);
  ushort_t* wab  = (ushort_t*)alloc((size_t)3 * DMODEL * DMODEL * 2);
  ushort_t* wpb  = (ushort_t*)alloc((size_t)DMODEL * DMODEL * 2);
  ushort_t* q_t  = (ushort_t*)alloc(MT * DMODEL * 2);
  ushort_t* k_t  = (ushort_t*)alloc(MT * DMODEL * 2);
  ushort_t* vtb  = (ushort_t*)alloc(MT * DMODEL * 2);
  ushort_t* yb   = (ushort_t*)alloc(MT * DMODEL * 2);
  float*    trig = (float*)alloc((size_t)T_SEQ * 64 * 2 * 4);
  (void)ws_size; (void)n_in; (void)in_sizes; (void)out_size;

  {  // one fused convert launch
    int n8x = (int)(MT * DMODEL / 8);
    int n8a = (int)((size_t)3 * DMODEL * DMODEL / 8);
    int n8p = (int)((size_t)DMODEL * DMODEL / 8);
    int tot = n8x + n8a + n8p;
    hipLaunchKernelGGL(cvt_all, dim3((tot + 255) / 256), dim3(256), 0, stream,
                       x, w_attn, w_proj, xb, wab, wpb, n8x, n8a, n8p);
  }
  hipLaunchKernelGGL(trig_init, dim3(T_SEQ * 64 / 256), dim3(256), 0, stream, trig);

  // QKV projection (256x128 R9 config): rope-fused q/k, LDS-transposed v
  hipLaunchKernelGGL((gemm_s<1>), dim3(3 * DMODEL / 128, MT / 256), dim3(512), 0, stream,
                     xb, wab, (float*)nullptr, q_t, k_t, vtb, trig,
                     (int)MT, 3 * DMODEL, DMODEL);

  hipLaunchKernelGGL(flash_attn, dim3(T_SEQ / 128, NB * NH), dim3(256), 0, stream,
                     q_t, k_t, vtb, yb);

  // output projection
  hipLaunchKernelGGL((gemm_s<0>), dim3(DMODEL / 128, MT / 256), dim3(512), 0, stream,
                     yb, wpb, out, (ushort_t*)nullptr, (ushort_t*)nullptr, (ushort_t*)nullptr,
                     (const float*)nullptr, (int)MT, DMODEL, DMODEL);
}

// Round 12
// 276.413 us; speedup vs baseline: 1.0661x; 1.0099x over previous
//
#include <hip/hip_runtime.h>
#include <hip/hip_bf16.h>

#define T_SEQ 2048
#define DMODEL 2048
#define NB 2
#define NH 16
#define HD 128

typedef __attribute__((ext_vector_type(8))) short short8;
typedef __attribute__((ext_vector_type(4))) float f32x4;
typedef __attribute__((ext_vector_type(16))) float f32x16;
typedef unsigned short ushort_t;

__device__ inline ushort_t f2bf(float f) {
  union { float f; unsigned u; } v; v.f = f;
  unsigned r = v.u + 0x7fffu + ((v.u >> 16) & 1u);
  return (ushort_t)(r >> 16);
}
__device__ inline float bf2f(ushort_t u) {
  union { unsigned u; float f; } v; v.u = ((unsigned)u) << 16;
  return v.f;
}
__device__ inline unsigned pk2(float x, float y) {
  union { __hip_bfloat162 h; unsigned u; } c;
  c.h = __float22bfloat162_rn(float2{x, y});
  return c.u;
}
__device__ inline float fexp2(float x) {
  float r;
  asm("v_exp_f32 %0, %1" : "=v"(r) : "v"(x));
  return r;
}

__device__ inline void gload16(const void* g, void* l) {
  __builtin_amdgcn_global_load_lds(
      (const __attribute__((address_space(1))) unsigned*)g,
      (__attribute__((address_space(3))) unsigned*)l, 16, 0, 0);
}

// ------------- fused fp32 -> bf16 convert (x, w_attn, w_proj) ---------
__global__ void cvt_all(const float* __restrict__ x, const float* __restrict__ wa,
                        const float* __restrict__ wp, ushort_t* __restrict__ xb,
                        ushort_t* __restrict__ wab, ushort_t* __restrict__ wpb,
                        int n8x, int n8a, int n8p) {
  int i = blockIdx.x * blockDim.x + threadIdx.x;
  const float* src; ushort_t* dst; int j;
  if (i < n8x)              { src = x;  dst = xb;  j = i; }
  else if (i < n8x + n8a)   { src = wa; dst = wab; j = i - n8x; }
  else if (i < n8x + n8a + n8p) { src = wp; dst = wpb; j = i - n8x - n8a; }
  else return;
  const float4* s = (const float4*)src + (size_t)j * 2;
  float4 a = s[0], b = s[1];
  short8 o;
  o[0] = (short)f2bf(a.x); o[1] = (short)f2bf(a.y);
  o[2] = (short)f2bf(a.z); o[3] = (short)f2bf(a.w);
  o[4] = (short)f2bf(b.x); o[5] = (short)f2bf(b.y);
  o[6] = (short)f2bf(b.z); o[7] = (short)f2bf(b.w);
  *((short8*)dst + j) = o;
}

// ---------------- cos/sin table: trig[t*128 + i*2]=cos, +1=sin --------
__global__ void trig_init(float* __restrict__ trig) {
  int idx = blockIdx.x * blockDim.x + threadIdx.x;  // T*64
  if (idx >= T_SEQ * 64) return;
  int i = idx & 63, t = idx >> 6;
  float inv = __expf(-(float)i * (9.210340371976184f / 64.0f));
  float f = (float)t * inv;
  trig[idx * 2]     = cosf(f);
  trig[idx * 2 + 1] = sinf(f);
}

// ===== 256x128 BK=32 double-buffered GEMM, m97 regime, 0-conflict =====
// (R9-verified config; R11 added fused V-transpose epilogue.)
// C = A[M][K] * Bt[N][K]^T. 512 thr = 8 waves (4M x 2N), per-wave 64x64.
// Per K-tile: {stage(kt+1 -> buf^1): 3 gload16 | 8 ds_read_b128 | 16 MFMA
// (setprio) | __syncthreads}. ONE barrier/K-tile; 2 blocks/CU hide drain.
// LDS: row pairs packed as 128B super-rows of 8 x 16B slots; row r chunk g
// at slot s = (((r&1)<<2)|g) ^ ((r>>1)&7); linear gload dest, decode on src.
// EPI=1 epilogue: q,k rope-fused scatter; v LDS-transposed -> vt[d][T].
template <int EPI>
__global__ __launch_bounds__(512, 4)
void gemm_s(const ushort_t* __restrict__ A, const ushort_t* __restrict__ Bt,
            float* __restrict__ C, ushort_t* __restrict__ q_t,
            ushort_t* __restrict__ k_t, ushort_t* __restrict__ v_t,
            const float* __restrict__ trig, int M, int N, int K) {
  __shared__ __align__(16) ushort_t sA[2][256 * 32];  // 2 x 16KB
  __shared__ __align__(16) ushort_t sB[2][128 * 32];  // 2 x 8KB
  int tid = threadIdx.x, lane = tid & 63, w = tid >> 6;
  int wm = w >> 1, wn = w & 1;
  int li = lane & 15, lg = lane >> 4;
  int tile_m = blockIdx.y * 256, tile_n = blockIdx.x * 128;
  const ushort_t* Ag = A + (size_t)tile_m * K;
  const ushort_t* Bg = Bt + (size_t)tile_n * K;

  // stage decode: lane's linear LDS slot -> global (row, chunk)
  int Rl = tid >> 3;           // superrow within instruction span
  int sl = tid & 7;            // slot
  int tdec = sl ^ (Rl & 7);
  int prow = (tdec >> 2) & 1, gch = tdec & 3;

  auto stage = [&](int kt, int buf) {
#pragma unroll
    for (int i = 0; i < 2; ++i) {  // A: 2 instrs x 64 superrows (128 rows)
      int grow = (i * 64 + Rl) * 2 + prow;
      gload16(Ag + (size_t)grow * K + kt * 32 + gch * 8,
              &sA[buf][i * 4096 + tid * 8]);
    }
    {                              // B: 1 instr x 64 superrows (128 rows)
      int grow = Rl * 2 + prow;
      gload16(Bg + (size_t)grow * K + kt * 32 + gch * 8,
              &sB[buf][tid * 8]);
    }
  };

  // read addressing: row r, global chunk lg -> element offset
  auto rdoff = [&](int r) {
    int R = r >> 1;
    int s = (((r & 1) << 2) | lg) ^ (R & 7);
    return R * 64 + s * 8;
  };

  f32x4 acc[4][4] = {};
  const int NT = K / 32;

  stage(0, 0);
  __syncthreads();

  for (int kt = 0; kt < NT; ++kt) {
    int cur = kt & 1;
    if (kt + 1 < NT) stage(kt + 1, cur ^ 1);
    short8 af[4], bf[4];
#pragma unroll
    for (int mi = 0; mi < 4; ++mi)
      af[mi] = *(const short8*)&sA[cur][rdoff(wm * 64 + mi * 16 + li)];
#pragma unroll
    for (int ni = 0; ni < 4; ++ni)
      bf[ni] = *(const short8*)&sB[cur][rdoff(wn * 64 + ni * 16 + li)];
    __builtin_amdgcn_s_setprio(1);
#pragma unroll
    for (int mi = 0; mi < 4; ++mi)
#pragma unroll
      for (int ni = 0; ni < 4; ++ni)
        acc[mi][ni] = __builtin_amdgcn_mfma_f32_16x16x32_bf16(af[mi], bf[ni], acc[mi][ni], 0, 0, 0);
    __builtin_amdgcn_s_setprio(0);
    __syncthreads();   // drains vmcnt(0)+lgkmcnt(0): buf^1 writes landed
  }

  if (EPI == 0) {
#pragma unroll
    for (int mi = 0; mi < 4; ++mi) {
      int trow = tile_m + wm * 64 + mi * 16 + lg * 4;
#pragma unroll
      for (int ni = 0; ni < 4; ++ni) {
        int col = tile_n + wn * 64 + ni * 16 + li;
#pragma unroll
        for (int r = 0; r < 4; ++r)
          C[(size_t)(trow + r) * N + col] = acc[mi][ni][r];
      }
    }
  } else {
    int sec = tile_n >> 11;          // block-uniform (128-wide tile, one head)
    int bq  = tile_m >> 11;
    int t0  = tile_m & 2047;
    int h   = (tile_n & 2047) >> 7;
    if (sec < 2) {
      ushort_t* base = ((sec == 0) ? q_t : k_t) + ((size_t)(bq * NH + h)) * T_SEQ * HD;
#pragma unroll
      for (int mi = 0; mi < 4; ++mi) {
        int tl = wm * 64 + mi * 16 + lg * 4;
#pragma unroll
        for (int ni = 0; ni < 4; ++ni) {
          int d = wn * 64 + ni * 16 + li;
          int fi2 = (d >> 1) * 2;
#pragma unroll
          for (int r = 0; r < 4; ++r) {
            int t = t0 + tl + r;
            float val = acc[mi][ni][r];
            float par = __shfl_xor(val, 1);
            const float* tp = trig + t * 128 + fi2;
            float c = tp[0], s = tp[1];
            float outv = (li & 1) ? (par * s + val * c) : (val * c - par * s);
            base[(size_t)t * HD + d] = f2bf(outv);
          }
        }
      }
    } else {
      // V: LDS-transpose the 256(t) x 128(d) tile in 4 chunks of 64 t-rows,
      // store vt[bh][d][T] coalesced. Reuses sA as padded [128][72] buffer.
      ushort_t* vbase = v_t + ((size_t)(bq * NH + h)) * HD * T_SEQ;
      ushort_t* L = (ushort_t*)sA;
      for (int c = 0; c < 4; ++c) {
        if (wm == c) {
#pragma unroll
          for (int mi = 0; mi < 4; ++mi) {
            int tl = mi * 16 + lg * 4;
#pragma unroll
            for (int ni = 0; ni < 4; ++ni) {
              int d = wn * 64 + ni * 16 + li;
#pragma unroll
              for (int r = 0; r < 4; ++r)
                L[d * 72 + tl + r] = f2bf(acc[mi][ni][r]);
            }
          }
        }
        __syncthreads();
#pragma unroll
        for (int j = 0; j < 2; ++j) {
          int idx = j * 512 + tid;
          int d = idx >> 3, tg = (idx & 7) * 8;
          short8 val = *(const short8*)&L[d * 72 + tg];
          *(short8*)(vbase + (size_t)d * T_SEQ + t0 + c * 64 + tg) = val;
        }
        __syncthreads();
      }
    }
  }
}

// ---------------- Flash attention (causal), swapped-QK 32x32 ----------
// 1D grid of 512 blocks, XCD-affine decode: each XCD owns 4 heads x all 16
// q-tiles (16 q-blocks of a head share its 1MB K/V panel -> L2-resident
// per-XCD instead of 8x-refetched across XCDs). Round-2 qi mirror keeps
// per-CU work uniform (2qi+2 + 2(15-qi)+2 = 36 tiles).
__global__ __launch_bounds__(256, 2)
void flash_attn(const ushort_t* __restrict__ Q, const ushort_t* __restrict__ Kg,
                const ushort_t* __restrict__ Vt, ushort_t* __restrict__ Y) {
  __shared__ __align__(16) ushort_t ldsK[2 * 64 * 128];   // 32KB, 2 buf
  __shared__ __align__(16) ushort_t ldsV[2 * 128 * 64];   // 32KB, 2 buf
  int tid = threadIdx.x, lane = tid & 63, w = tid >> 6;
  int hi = lane >> 5, l31 = lane & 31;
  int f = blockIdx.x;
  int xcd = f & 7, j = f >> 3;
  int bh = (xcd << 2) | (j >> 4);          // 4 heads per XCD
  int jq = j & 15;
  int qi = (j & 32) ? (15 - jq) : jq;      // mirror second CU-round
  int b = bh >> 4, h = bh & 15;
  int q0 = qi * 128;
  const ushort_t* Qp = Q + (size_t)bh * T_SEQ * HD;
  const ushort_t* Kp = Kg + (size_t)bh * T_SEQ * HD;
  const ushort_t* Vp = Vt + (size_t)bh * HD * T_SEQ;

  int qg = q0 + w * 32 + l31;
  int qmaxw = q0 + w * 32 + 31;

  auto stage = [&](int kv0, int bsel) {
    ushort_t* Kb = ldsK + bsel * 8192;
    ushort_t* Vb = ldsV + bsel * 8192;
#pragma unroll
    for (int p = 0; p < 4; ++p) {
      int c = p * 256 + w * 64 + lane;
      {
        int row = c >> 4, cc = c & 15;
        int sc = cc ^ (row & 15);
        gload16(Kp + (size_t)(kv0 + row) * HD + sc * 8, Kb + (p * 256 + w * 64) * 8);
      }
      {
        int d = c >> 3, cc = c & 7;
        int sc = cc ^ (d & 7);
        gload16(Vp + (size_t)d * T_SEQ + kv0 + sc * 8, Vb + (p * 256 + w * 64) * 8);
      }
    }
  };

  short8 qf[8];
#pragma unroll
  for (int ds = 0; ds < 8; ++ds)
    qf[ds] = *(const short8*)(Qp + (size_t)qg * HD + ds * 16 + hi * 8);

  f32x16 o[4] = {};
  float mu = -1e30f, l = 0.f;
  const float SIG = 0.12751879523209784f;  // (1/sqrt(128)) * log2(e)

  int nkt = 2 * qi + 2;
  stage(0, 0);
  __syncthreads();
  int cur = 0;
  for (int kt = 0; kt < nkt; ++kt) {
    int kv0 = kt * 64;
    if (kt + 1 < nkt) stage((kt + 1) * 64, cur ^ 1);
    if (kv0 <= qmaxw) {
      const ushort_t* Kb = ldsK + cur * 8192;
      const ushort_t* Vb = ldsV + cur * 8192;
      f32x16 sa = {}, sb = {};
      __builtin_amdgcn_s_setprio(1);
#pragma unroll
      for (int ds = 0; ds < 8; ++ds) {
        int cc = ds * 2 + hi;
        short8 k0 = *(const short8*)&Kb[l31 * 128 + ((cc ^ (l31 & 15)) * 8)];
        short8 k1 = *(const short8*)&Kb[(32 + l31) * 128 + ((cc ^ (l31 & 15)) * 8)];
        sa = __builtin_amdgcn_mfma_f32_32x32x16_bf16(k0, qf[ds], sa, 0, 0, 0);
        sb = __builtin_amdgcn_mfma_f32_32x32x16_bf16(k1, qf[ds], sb, 0, 0, 0);
      }
      __builtin_amdgcn_s_setprio(0);
      float p[32];
#pragma unroll
      for (int r = 0; r < 16; ++r) { p[r] = sa[r] * SIG; p[16 + r] = sb[r] * SIG; }
      if (kv0 + 63 > q0 + w * 32) {
#pragma unroll
        for (int r = 0; r < 16; ++r) {
          int loc = (r & 3) + 8 * (r >> 2) + 4 * hi;
          if (kv0 + loc > qg)      p[r]      = -3e38f;
          if (kv0 + 32 + loc > qg) p[16 + r] = -3e38f;
        }
      }
      float tm[16];
#pragma unroll
      for (int i = 0; i < 16; ++i) tm[i] = fmaxf(p[i], p[i + 16]);
#pragma unroll
      for (int st = 8; st >= 1; st >>= 1)
#pragma unroll
        for (int i = 0; i < 8; ++i)
          if (i < st) tm[i] = fmaxf(tm[i], tm[i + st]);
      float pmax = fmaxf(tm[0], __shfl_xor(tm[0], 32));
      bool resc = !__all(pmax <= mu + 11.0f);
      if (resc) {
        float munew = fmaxf(mu, pmax);
        float alpha = fexp2(mu - munew);
        mu = munew;
        l *= alpha;
#pragma unroll
        for (int dsub = 0; dsub < 4; ++dsub)
#pragma unroll
          for (int r = 0; r < 16; ++r) o[dsub][r] *= alpha;
      }
#pragma unroll
      for (int i = 0; i < 32; ++i) p[i] = fexp2(p[i] - mu);
      float ts[16];
#pragma unroll
      for (int i = 0; i < 16; ++i) ts[i] = p[i] + p[i + 16];
#pragma unroll
      for (int st = 8; st >= 1; st >>= 1)
#pragma unroll
        for (int i = 0; i < 8; ++i)
          if (i < st) ts[i] += ts[i + st];
      l += ts[0] + __shfl_xor(ts[0], 32);
      __builtin_amdgcn_s_setprio(1);
#pragma unroll
      for (int s = 0; s < 4; ++s) {
        int rb = (s >> 1) * 16 + (s & 1) * 8;
        unsigned a0 = pk2(p[rb + 0], p[rb + 1]);
        unsigned a1 = pk2(p[rb + 2], p[rb + 3]);
        unsigned a2 = pk2(p[rb + 4], p[rb + 5]);
        unsigned a3 = pk2(p[rb + 6], p[rb + 7]);
        unsigned sa0 = (unsigned)__shfl_xor((int)a0, 32);
        unsigned sa1 = (unsigned)__shfl_xor((int)a1, 32);
        unsigned sa2 = (unsigned)__shfl_xor((int)a2, 32);
        unsigned sa3 = (unsigned)__shfl_xor((int)a3, 32);
        union { unsigned u[4]; short8 s8; } pf;
        pf.u[0] = hi ? sa2 : a0;
        pf.u[1] = hi ? sa3 : a1;
        pf.u[2] = hi ? a2 : sa0;
        pf.u[3] = hi ? a3 : sa1;
#pragma unroll
        for (int dsub = 0; dsub < 4; ++dsub) {
          int row = dsub * 32 + l31;
          short8 vf = *(const short8*)&Vb[row * 64 + (((2 * s + hi) ^ (row & 7)) * 8)];
          o[dsub] = __builtin_amdgcn_mfma_f32_32x32x16_bf16(vf, pf.s8, o[dsub], 0, 0, 0);
        }
      }
      __builtin_amdgcn_s_setprio(0);
    }
    __syncthreads();
    cur ^= 1;
  }
  float invl = 1.f / l;
#pragma unroll
  for (int dsub = 0; dsub < 4; ++dsub)
#pragma unroll
    for (int r = 0; r < 16; ++r) o[dsub][r] *= invl;
#pragma unroll
  for (int dsub = 0; dsub < 4; ++dsub)
#pragma unroll
    for (int r = 0; r < 16; r += 2) {
      int d0 = dsub * 32 + (r & 3) + 8 * (r >> 2) + 4 * hi;
      unsigned u = pk2(o[dsub][r], o[dsub][r + 1]);
      *(unsigned*)&ldsK[w * 4096 + l31 * 128 + (((d0 >> 3) ^ (l31 & 15)) * 8) + (d0 & 7)] = u;
    }
  __syncthreads();
#pragma unroll
  for (int rep = 0; rep < 8; ++rep) {
    int idx = rep * 256 + tid;
    int qg2 = idx >> 4, c = idx & 15;
    int wv2 = qg2 >> 5, ql = qg2 & 31;
    short8 val = *(const short8*)&ldsK[wv2 * 4096 + ql * 128 + ((c ^ (ql & 15)) * 8)];
    *(short8*)(Y + ((size_t)(b * T_SEQ + q0 + qg2)) * DMODEL + h * HD + c * 8) = val;
  }
}

extern "C" void kernel_launch(void* const* d_in, const int* in_sizes, int n_in,
                              void* d_out, int out_size, void* d_ws, size_t ws_size,
                              hipStream_t stream) {
  const float* x      = (const float*)d_in[0];
  const float* w_attn = (const float*)d_in[1];
  const float* w_proj = (const float*)d_in[2];
  float* out = (float*)d_out;

  char* ws = (char*)d_ws;
  size_t off = 0;
  auto alloc = [&](size_t bytes) -> void* {
    void* p = ws + off;
    off = (off + bytes + 255) & ~(size_t)255;
    return p;
  };
  const size_t MT = (size_t)NB * T_SEQ;          // 4096
  ushort_t* xb   = (ushort_t*)alloc(MT * DMODEL * 2);
  ushort_t* wab  = (ushort_t*)alloc((size_t)3 * DMODEL * DMODEL * 2);
  ushort_t* wpb  = (ushort_t*)alloc((size_t)DMODEL * DMODEL * 2);
  ushort_t* q_t  = (ushort_t*)alloc(MT * DMODEL * 2);
  ushort_t* k_t  = (ushort_t*)alloc(MT * DMODEL * 2);
  ushort_t* vtb  = (ushort_t*)alloc(MT * DMODEL * 2);
  ushort_t* yb   = (ushort_t*)alloc(MT * DMODEL * 2);
  float*    trig = (float*)alloc((size_t)T_SEQ * 64 * 2 * 4);
  (void)ws_size; (void)n_in; (void)in_sizes; (void)out_size;

  {  // one fused convert launch
    int n8x = (int)(MT * DMODEL / 8);
    int n8a = (int)((size_t)3 * DMODEL * DMODEL / 8);
    int n8p = (int)((size_t)DMODEL * DMODEL / 8);
    int tot = n8x + n8a + n8p;
    hipLaunchKernelGGL(cvt_all, dim3((tot + 255) / 256), dim3(256), 0, stream,
                       x, w_attn, w_proj, xb, wab, wpb, n8x, n8a, n8p);
  }
  hipLaunchKernelGGL(trig_init, dim3(T_SEQ * 64 / 256), dim3(256), 0, stream, trig);

  // QKV projection (256x128 R9 config): rope-fused q/k, LDS-transposed v
  hipLaunchKernelGGL((gemm_s<1>), dim3(3 * DMODEL / 128, MT / 256), dim3(512), 0, stream,
                     xb, wab, (float*)nullptr, q_t, k_t, vtb, trig,
                     (int)MT, 3 * DMODEL, DMODEL);

  // flash attention: 1D grid, XCD-affine head placement
  hipLaunchKernelGGL(flash_attn, dim3(512), dim3(256), 0, stream,
                     q_t, k_t, vtb, yb);

  // output projection
  hipLaunchKernelGGL((gemm_s<0>), dim3(DMODEL / 128, MT / 256), dim3(512), 0, stream,
                     yb, wpb, out, (ushort_t*)nullptr, (ushort_t*)nullptr, (ushort_t*)nullptr,
                     (const float*)nullptr, (int)MT, DMODEL, DMODEL);
}

// Round 13
// 266.372 us; speedup vs baseline: 1.1063x; 1.0377x over previous
//
#include <hip/hip_runtime.h>
#include <hip/hip_bf16.h>

#define T_SEQ 2048
#define DMODEL 2048
#define NB 2
#define NH 16
#define HD 128

typedef __attribute__((ext_vector_type(8))) short short8;
typedef __attribute__((ext_vector_type(4))) float f32x4;
typedef __attribute__((ext_vector_type(16))) float f32x16;
typedef unsigned short ushort_t;

__device__ inline ushort_t f2bf(float f) {
  union { float f; unsigned u; } v; v.f = f;
  unsigned r = v.u + 0x7fffu + ((v.u >> 16) & 1u);
  return (ushort_t)(r >> 16);
}
__device__ inline float bf2f(ushort_t u) {
  union { unsigned u; float f; } v; v.u = ((unsigned)u) << 16;
  return v.f;
}
__device__ inline unsigned pk2(float x, float y) {
  union { __hip_bfloat162 h; unsigned u; } c;
  c.h = __float22bfloat162_rn(float2{x, y});
  return c.u;
}
__device__ inline float fexp2(float x) {
  float r;
  asm("v_exp_f32 %0, %1" : "=v"(r) : "v"(x));
  return r;
}

__device__ inline void gload16(const void* g, void* l) {
  __builtin_amdgcn_global_load_lds(
      (const __attribute__((address_space(1))) unsigned*)g,
      (__attribute__((address_space(3))) unsigned*)l, 16, 0, 0);
}

// --- fused fp32->bf16 convert (x, w_attn, w_proj) + trig table init ---
__global__ void cvt_all(const float* __restrict__ x, const float* __restrict__ wa,
                        const float* __restrict__ wp, ushort_t* __restrict__ xb,
                        ushort_t* __restrict__ wab, ushort_t* __restrict__ wpb,
                        float* __restrict__ trig, int n8x, int n8a, int n8p) {
  int i = blockIdx.x * blockDim.x + threadIdx.x;
  const float* src; ushort_t* dst; int j;
  if (i < n8x)                  { src = x;  dst = xb;  j = i; }
  else if (i < n8x + n8a)       { src = wa; dst = wab; j = i - n8x; }
  else if (i < n8x + n8a + n8p) { src = wp; dst = wpb; j = i - n8x - n8a; }
  else {
    int idx = i - n8x - n8a - n8p;       // trig region: T*64 entries
    if (idx >= T_SEQ * 64) return;
    int fi = idx & 63, t = idx >> 6;
    float inv = __expf(-(float)fi * (9.210340371976184f / 64.0f));
    float f = (float)t * inv;
    trig[idx * 2]     = cosf(f);
    trig[idx * 2 + 1] = sinf(f);
    return;
  }
  const float4* s = (const float4*)src + (size_t)j * 2;
  float4 a = s[0], b = s[1];
  short8 o;
  o[0] = (short)f2bf(a.x); o[1] = (short)f2bf(a.y);
  o[2] = (short)f2bf(a.z); o[3] = (short)f2bf(a.w);
  o[4] = (short)f2bf(b.x); o[5] = (short)f2bf(b.y);
  o[6] = (short)f2bf(b.z); o[7] = (short)f2bf(b.w);
  *((short8*)dst + j) = o;
}

// ===== 256x128 BK=32 double-buffered GEMM, m97 regime, 0-conflict =====
// (R9-verified; R11 added fused V-transpose epilogue.) 512 thr = 8 waves
// (4M x 2N), per-wave 64x64. ONE barrier/K-tile; 3 blocks/CU (QKV grid 768)
// hide the drain. LDS: row pairs packed as 128B super-rows of 8 x 16B
// slots; row r chunk g at slot s = (((r&1)<<2)|g) ^ ((r>>1)&7).
// EPI=1 epilogue: q,k rope-fused scatter; v LDS-transposed -> vt[d][T].
template <int EPI>
__global__ __launch_bounds__(512, 4)
void gemm_s(const ushort_t* __restrict__ A, const ushort_t* __restrict__ Bt,
            float* __restrict__ C, ushort_t* __restrict__ q_t,
            ushort_t* __restrict__ k_t, ushort_t* __restrict__ v_t,
            const float* __restrict__ trig, int M, int N, int K) {
  __shared__ __align__(16) ushort_t sA[2][256 * 32];  // 2 x 16KB
  __shared__ __align__(16) ushort_t sB[2][128 * 32];  // 2 x 8KB
  int tid = threadIdx.x, lane = tid & 63, w = tid >> 6;
  int wm = w >> 1, wn = w & 1;
  int li = lane & 15, lg = lane >> 4;
  int tile_m = blockIdx.y * 256, tile_n = blockIdx.x * 128;
  const ushort_t* Ag = A + (size_t)tile_m * K;
  const ushort_t* Bg = Bt + (size_t)tile_n * K;

  int Rl = tid >> 3;
  int sl = tid & 7;
  int tdec = sl ^ (Rl & 7);
  int prow = (tdec >> 2) & 1, gch = tdec & 3;

  auto stage = [&](int kt, int buf) {
#pragma unroll
    for (int i = 0; i < 2; ++i) {
      int grow = (i * 64 + Rl) * 2 + prow;
      gload16(Ag + (size_t)grow * K + kt * 32 + gch * 8,
              &sA[buf][i * 4096 + tid * 8]);
    }
    {
      int grow = Rl * 2 + prow;
      gload16(Bg + (size_t)grow * K + kt * 32 + gch * 8,
              &sB[buf][tid * 8]);
    }
  };

  auto rdoff = [&](int r) {
    int R = r >> 1;
    int s = (((r & 1) << 2) | lg) ^ (R & 7);
    return R * 64 + s * 8;
  };

  f32x4 acc[4][4] = {};
  const int NT = K / 32;

  stage(0, 0);
  __syncthreads();

  for (int kt = 0; kt < NT; ++kt) {
    int cur = kt & 1;
    if (kt + 1 < NT) stage(kt + 1, cur ^ 1);
    short8 af[4], bf[4];
#pragma unroll
    for (int mi = 0; mi < 4; ++mi)
      af[mi] = *(const short8*)&sA[cur][rdoff(wm * 64 + mi * 16 + li)];
#pragma unroll
    for (int ni = 0; ni < 4; ++ni)
      bf[ni] = *(const short8*)&sB[cur][rdoff(wn * 64 + ni * 16 + li)];
    __builtin_amdgcn_s_setprio(1);
#pragma unroll
    for (int mi = 0; mi < 4; ++mi)
#pragma unroll
      for (int ni = 0; ni < 4; ++ni)
        acc[mi][ni] = __builtin_amdgcn_mfma_f32_16x16x32_bf16(af[mi], bf[ni], acc[mi][ni], 0, 0, 0);
    __builtin_amdgcn_s_setprio(0);
    __syncthreads();
  }

  if (EPI == 0) {
#pragma unroll
    for (int mi = 0; mi < 4; ++mi) {
      int trow = tile_m + wm * 64 + mi * 16 + lg * 4;
#pragma unroll
      for (int ni = 0; ni < 4; ++ni) {
        int col = tile_n + wn * 64 + ni * 16 + li;
#pragma unroll
        for (int r = 0; r < 4; ++r)
          C[(size_t)(trow + r) * N + col] = acc[mi][ni][r];
      }
    }
  } else {
    int sec = tile_n >> 11;
    int bq  = tile_m >> 11;
    int t0  = tile_m & 2047;
    int h   = (tile_n & 2047) >> 7;
    if (sec < 2) {
      ushort_t* base = ((sec == 0) ? q_t : k_t) + ((size_t)(bq * NH + h)) * T_SEQ * HD;
#pragma unroll
      for (int mi = 0; mi < 4; ++mi) {
        int tl = wm * 64 + mi * 16 + lg * 4;
#pragma unroll
        for (int ni = 0; ni < 4; ++ni) {
          int d = wn * 64 + ni * 16 + li;
          int fi2 = (d >> 1) * 2;
#pragma unroll
          for (int r = 0; r < 4; ++r) {
            int t = t0 + tl + r;
            float val = acc[mi][ni][r];
            float par = __shfl_xor(val, 1);
            const float* tp = trig + t * 128 + fi2;
            float c = tp[0], s = tp[1];
            float outv = (li & 1) ? (par * s + val * c) : (val * c - par * s);
            base[(size_t)t * HD + d] = f2bf(outv);
          }
        }
      }
    } else {
      // V: LDS-transpose 256(t) x 128(d) tile in 4 chunks of 64 t-rows.
      ushort_t* vbase = v_t + ((size_t)(bq * NH + h)) * HD * T_SEQ;
      ushort_t* L = (ushort_t*)sA;
      for (int c = 0; c < 4; ++c) {
        if (wm == c) {
#pragma unroll
          for (int mi = 0; mi < 4; ++mi) {
            int tl = mi * 16 + lg * 4;
#pragma unroll
            for (int ni = 0; ni < 4; ++ni) {
              int d = wn * 64 + ni * 16 + li;
#pragma unroll
              for (int r = 0; r < 4; ++r)
                L[d * 72 + tl + r] = f2bf(acc[mi][ni][r]);
            }
          }
        }
        __syncthreads();
#pragma unroll
        for (int j = 0; j < 2; ++j) {
          int idx = j * 512 + tid;
          int d = idx >> 3, tg = (idx & 7) * 8;
          short8 val = *(const short8*)&L[d * 72 + tg];
          *(short8*)(vbase + (size_t)d * T_SEQ + t0 + c * 64 + tg) = val;
        }
        __syncthreads();
      }
    }
  }
}

// ===== 128x128 BK=32 double-buffered GEMM (R10-proven) — for proj =====
// 256 thr = 4 waves (2M x 2N). Same super-row conflict-free LDS map.
// At proj's shape (N=2048): grid 16x32 = 512 blocks = 2/CU resident
// (vs 256x128's 256 blocks = 1/CU) -> cross-block overlap restored.
__global__ __launch_bounds__(256, 4)
void gemm_s128(const ushort_t* __restrict__ A, const ushort_t* __restrict__ Bt,
               float* __restrict__ C, int M, int N, int K) {
  __shared__ __align__(16) ushort_t sA[2][128 * 32];  // 2 x 8KB
  __shared__ __align__(16) ushort_t sB[2][128 * 32];  // 2 x 8KB
  int tid = threadIdx.x, lane = tid & 63, w = tid >> 6;
  int wm = w >> 1, wn = w & 1;
  int li = lane & 15, lg = lane >> 4;
  int tile_m = blockIdx.y * 128, tile_n = blockIdx.x * 128;
  const ushort_t* Ag = A + (size_t)tile_m * K;
  const ushort_t* Bg = Bt + (size_t)tile_n * K;

  int Rl = tid >> 3;           // 0..31
  int sl = tid & 7;
  int tdec = sl ^ (Rl & 7);
  int prow = (tdec >> 2) & 1, gch = tdec & 3;

  auto stage = [&](int kt, int buf) {
#pragma unroll
    for (int i = 0; i < 2; ++i) {
      int grow = (i * 32 + Rl) * 2 + prow;
      gload16(Ag + (size_t)grow * K + kt * 32 + gch * 8,
              &sA[buf][i * 2048 + tid * 8]);
    }
#pragma unroll
    for (int i = 0; i < 2; ++i) {
      int grow = (i * 32 + Rl) * 2 + prow;
      gload16(Bg + (size_t)grow * K + kt * 32 + gch * 8,
              &sB[buf][i * 2048 + tid * 8]);
    }
  };

  auto rdoff = [&](int r) {
    int R = r >> 1;
    int s = (((r & 1) << 2) | lg) ^ (R & 7);
    return R * 64 + s * 8;
  };

  f32x4 acc[4][4] = {};
  const int NT = K / 32;

  stage(0, 0);
  __syncthreads();

  for (int kt = 0; kt < NT; ++kt) {
    int cur = kt & 1;
    if (kt + 1 < NT) stage(kt + 1, cur ^ 1);
    short8 af[4], bf[4];
#pragma unroll
    for (int mi = 0; mi < 4; ++mi)
      af[mi] = *(const short8*)&sA[cur][rdoff(wm * 64 + mi * 16 + li)];
#pragma unroll
    for (int ni = 0; ni < 4; ++ni)
      bf[ni] = *(const short8*)&sB[cur][rdoff(wn * 64 + ni * 16 + li)];
    __builtin_amdgcn_s_setprio(1);
#pragma unroll
    for (int mi = 0; mi < 4; ++mi)
#pragma unroll
      for (int ni = 0; ni < 4; ++ni)
        acc[mi][ni] = __builtin_amdgcn_mfma_f32_16x16x32_bf16(af[mi], bf[ni], acc[mi][ni], 0, 0, 0);
    __builtin_amdgcn_s_setprio(0);
    __syncthreads();
  }

#pragma unroll
  for (int mi = 0; mi < 4; ++mi) {
    int trow = tile_m + wm * 64 + mi * 16 + lg * 4;
#pragma unroll
    for (int ni = 0; ni < 4; ++ni) {
      int col = tile_n + wn * 64 + ni * 16 + li;
#pragma unroll
      for (int r = 0; r < 4; ++r)
        C[(size_t)(trow + r) * N + col] = acc[mi][ni][r];
    }
  }
}

// ---------------- Flash attention (causal), swapped-QK 32x32 ----------
// 1D grid of 512 blocks, XCD-affine decode (R12): each XCD owns 4 heads x
// all 16 q-tiles; round-2 qi mirror keeps per-CU work uniform.
__global__ __launch_bounds__(256, 2)
void flash_attn(const ushort_t* __restrict__ Q, const ushort_t* __restrict__ Kg,
                const ushort_t* __restrict__ Vt, ushort_t* __restrict__ Y) {
  __shared__ __align__(16) ushort_t ldsK[2 * 64 * 128];   // 32KB, 2 buf
  __shared__ __align__(16) ushort_t ldsV[2 * 128 * 64];   // 32KB, 2 buf
  int tid = threadIdx.x, lane = tid & 63, w = tid >> 6;
  int hi = lane >> 5, l31 = lane & 31;
  int f = blockIdx.x;
  int xcd = f & 7, j = f >> 3;
  int bh = (xcd << 2) | (j >> 4);
  int jq = j & 15;
  int qi = (j & 32) ? (15 - jq) : jq;
  int b = bh >> 4, h = bh & 15;
  int q0 = qi * 128;
  const ushort_t* Qp = Q + (size_t)bh * T_SEQ * HD;
  const ushort_t* Kp = Kg + (size_t)bh * T_SEQ * HD;
  const ushort_t* Vp = Vt + (size_t)bh * HD * T_SEQ;

  int qg = q0 + w * 32 + l31;
  int qmaxw = q0 + w * 32 + 31;

  auto stage = [&](int kv0, int bsel) {
    ushort_t* Kb = ldsK + bsel * 8192;
    ushort_t* Vb = ldsV + bsel * 8192;
#pragma unroll
    for (int p = 0; p < 4; ++p) {
      int c = p * 256 + w * 64 + lane;
      {
        int row = c >> 4, cc = c & 15;
        int sc = cc ^ (row & 15);
        gload16(Kp + (size_t)(kv0 + row) * HD + sc * 8, Kb + (p * 256 + w * 64) * 8);
      }
      {
        int d = c >> 3, cc = c & 7;
        int sc = cc ^ (d & 7);
        gload16(Vp + (size_t)d * T_SEQ + kv0 + sc * 8, Vb + (p * 256 + w * 64) * 8);
      }
    }
  };

  short8 qf[8];
#pragma unroll
  for (int ds = 0; ds < 8; ++ds)
    qf[ds] = *(const short8*)(Qp + (size_t)qg * HD + ds * 16 + hi * 8);

  f32x16 o[4] = {};
  float mu = -1e30f, l = 0.f;
  const float SIG = 0.12751879523209784f;  // (1/sqrt(128)) * log2(e)

  int nkt = 2 * qi + 2;
  stage(0, 0);
  __syncthreads();
  int cur = 0;
  for (int kt = 0; kt < nkt; ++kt) {
    int kv0 = kt * 64;
    if (kt + 1 < nkt) stage((kt + 1) * 64, cur ^ 1);
    if (kv0 <= qmaxw) {
      const ushort_t* Kb = ldsK + cur * 8192;
      const ushort_t* Vb = ldsV + cur * 8192;
      f32x16 sa = {}, sb = {};
      __builtin_amdgcn_s_setprio(1);
#pragma unroll
      for (int ds = 0; ds < 8; ++ds) {
        int cc = ds * 2 + hi;
        short8 k0 = *(const short8*)&Kb[l31 * 128 + ((cc ^ (l31 & 15)) * 8)];
        short8 k1 = *(const short8*)&Kb[(32 + l31) * 128 + ((cc ^ (l31 & 15)) * 8)];
        sa = __builtin_amdgcn_mfma_f32_32x32x16_bf16(k0, qf[ds], sa, 0, 0, 0);
        sb = __builtin_amdgcn_mfma_f32_32x32x16_bf16(k1, qf[ds], sb, 0, 0, 0);
      }
      __builtin_amdgcn_s_setprio(0);
      float p[32];
#pragma unroll
      for (int r = 0; r < 16; ++r) { p[r] = sa[r] * SIG; p[16 + r] = sb[r] * SIG; }
      if (kv0 + 63 > q0 + w * 32) {
#pragma unroll
        for (int r = 0; r < 16; ++r) {
          int loc = (r & 3) + 8 * (r >> 2) + 4 * hi;
          if (kv0 + loc > qg)      p[r]      = -3e38f;
          if (kv0 + 32 + loc > qg) p[16 + r] = -3e38f;
        }
      }
      float tm[16];
#pragma unroll
      for (int i = 0; i < 16; ++i) tm[i] = fmaxf(p[i], p[i + 16]);
#pragma unroll
      for (int st = 8; st >= 1; st >>= 1)
#pragma unroll
        for (int i = 0; i < 8; ++i)
          if (i < st) tm[i] = fmaxf(tm[i], tm[i + st]);
      float pmax = fmaxf(tm[0], __shfl_xor(tm[0], 32));
      bool resc = !__all(pmax <= mu + 11.0f);
      if (resc) {
        float munew = fmaxf(mu, pmax);
        float alpha = fexp2(mu - munew);
        mu = munew;
        l *= alpha;
#pragma unroll
        for (int dsub = 0; dsub < 4; ++dsub)
#pragma unroll
          for (int r = 0; r < 16; ++r) o[dsub][r] *= alpha;
      }
#pragma unroll
      for (int i = 0; i < 32; ++i) p[i] = fexp2(p[i] - mu);
      float ts[16];
#pragma unroll
      for (int i = 0; i < 16; ++i) ts[i] = p[i] + p[i + 16];
#pragma unroll
      for (int st = 8; st >= 1; st >>= 1)
#pragma unroll
        for (int i = 0; i < 8; ++i)
          if (i < st) ts[i] += ts[i + st];
      l += ts[0] + __shfl_xor(ts[0], 32);
      __builtin_amdgcn_s_setprio(1);
#pragma unroll
      for (int s = 0; s < 4; ++s) {
        int rb = (s >> 1) * 16 + (s & 1) * 8;
        unsigned a0 = pk2(p[rb + 0], p[rb + 1]);
        unsigned a1 = pk2(p[rb + 2], p[rb + 3]);
        unsigned a2 = pk2(p[rb + 4], p[rb + 5]);
        unsigned a3 = pk2(p[rb + 6], p[rb + 7]);
        unsigned sa0 = (unsigned)__shfl_xor((int)a0, 32);
        unsigned sa1 = (unsigned)__shfl_xor((int)a1, 32);
        unsigned sa2 = (unsigned)__shfl_xor((int)a2, 32);
        unsigned sa3 = (unsigned)__shfl_xor((int)a3, 32);
        union { unsigned u[4]; short8 s8; } pf;
        pf.u[0] = hi ? sa2 : a0;
        pf.u[1] = hi ? sa3 : a1;
        pf.u[2] = hi ? a2 : sa0;
        pf.u[3] = hi ? a3 : sa1;
#pragma unroll
        for (int dsub = 0; dsub < 4; ++dsub) {
          int row = dsub * 32 + l31;
          short8 vf = *(const short8*)&Vb[row * 64 + (((2 * s + hi) ^ (row & 7)) * 8)];
          o[dsub] = __builtin_amdgcn_mfma_f32_32x32x16_bf16(vf, pf.s8, o[dsub], 0, 0, 0);
        }
      }
      __builtin_amdgcn_s_setprio(0);
    }
    __syncthreads();
    cur ^= 1;
  }
  float invl = 1.f / l;
#pragma unroll
  for (int dsub = 0; dsub < 4; ++dsub)
#pragma unroll
    for (int r = 0; r < 16; ++r) o[dsub][r] *= invl;
#pragma unroll
  for (int dsub = 0; dsub < 4; ++dsub)
#pragma unroll
    for (int r = 0; r < 16; r += 2) {
      int d0 = dsub * 32 + (r & 3) + 8 * (r >> 2) + 4 * hi;
      unsigned u = pk2(o[dsub][r], o[dsub][r + 1]);
      *(unsigned*)&ldsK[w * 4096 + l31 * 128 + (((d0 >> 3) ^ (l31 & 15)) * 8) + (d0 & 7)] = u;
    }
  __syncthreads();
#pragma unroll
  for (int rep = 0; rep < 8; ++rep) {
    int idx = rep * 256 + tid;
    int qg2 = idx >> 4, c = idx & 15;
    int wv2 = qg2 >> 5, ql = qg2 & 31;
    short8 val = *(const short8*)&ldsK[wv2 * 4096 + ql * 128 + ((c ^ (ql & 15)) * 8)];
    *(short8*)(Y + ((size_t)(b * T_SEQ + q0 + qg2)) * DMODEL + h * HD + c * 8) = val;
  }
}

extern "C" void kernel_launch(void* const* d_in, const int* in_sizes, int n_in,
                              void* d_out, int out_size, void* d_ws, size_t ws_size,
                              hipStream_t stream) {
  const float* x      = (const float*)d_in[0];
  const float* w_attn = (const float*)d_in[1];
  const float* w_proj = (const float*)d_in[2];
  float* out = (float*)d_out;

  char* ws = (char*)d_ws;
  size_t off = 0;
  auto alloc = [&](size_t bytes) -> void* {
    void* p = ws + off;
    off = (off + bytes + 255) & ~(size_t)255;
    return p;
  };
  const size_t MT = (size_t)NB * T_SEQ;          // 4096
  ushort_t* xb   = (ushort_t*)alloc(MT * DMODEL * 2);
  ushort_t* wab  = (ushort_t*)alloc((size_t)3 * DMODEL * DMODEL * 2);
  ushort_t* wpb  = (ushort_t*)alloc((size_t)DMODEL * DMODEL * 2);
  ushort_t* q_t  = (ushort_t*)alloc(MT * DMODEL * 2);
  ushort_t* k_t  = (ushort_t*)alloc(MT * DMODEL * 2);
  ushort_t* vtb  = (ushort_t*)alloc(MT * DMODEL * 2);
  ushort_t* yb   = (ushort_t*)alloc(MT * DMODEL * 2);
  float*    trig = (float*)alloc((size_t)T_SEQ * 64 * 2 * 4);
  (void)ws_size; (void)n_in; (void)in_sizes; (void)out_size;

  {  // one fused convert + trig launch
    int n8x = (int)(MT * DMODEL / 8);
    int n8a = (int)((size_t)3 * DMODEL * DMODEL / 8);
    int n8p = (int)((size_t)DMODEL * DMODEL / 8);
    int tot = n8x + n8a + n8p + T_SEQ * 64;
    hipLaunchKernelGGL(cvt_all, dim3((tot + 255) / 256), dim3(256), 0, stream,
                       x, w_attn, w_proj, xb, wab, wpb, trig, n8x, n8a, n8p);
  }

  // QKV projection (256x128 R9 config): rope-fused q/k, LDS-transposed v
  hipLaunchKernelGGL((gemm_s<1>), dim3(3 * DMODEL / 128, MT / 256), dim3(512), 0, stream,
                     xb, wab, (float*)nullptr, q_t, k_t, vtb, trig,
                     (int)MT, 3 * DMODEL, DMODEL);

  // flash attention: 1D grid, XCD-affine head placement
  hipLaunchKernelGGL(flash_attn, dim3(512), dim3(256), 0, stream,
                     q_t, k_t, vtb, yb);

  // output projection: 128^2 tile -> 512 blocks = 2/CU (overlap restored)
  hipLaunchKernelGGL(gemm_s128, dim3(DMODEL / 128, MT / 128), dim3(256), 0, stream,
                     yb, wpb, out, (int)MT, DMODEL, DMODEL);
}

// Round 14
// 265.716 us; speedup vs baseline: 1.1090x; 1.0025x over previous
//
#include <hip/hip_runtime.h>
#include <hip/hip_bf16.h>

#define T_SEQ 2048
#define DMODEL 2048
#define NB 2
#define NH 16
#define HD 128

typedef __attribute__((ext_vector_type(8))) short short8;
typedef __attribute__((ext_vector_type(4))) float f32x4;
typedef __attribute__((ext_vector_type(16))) float f32x16;
typedef unsigned short ushort_t;

__device__ inline ushort_t f2bf(float f) {
  union { float f; unsigned u; } v; v.f = f;
  unsigned r = v.u + 0x7fffu + ((v.u >> 16) & 1u);
  return (ushort_t)(r >> 16);
}
__device__ inline float bf2f(ushort_t u) {
  union { unsigned u; float f; } v; v.u = ((unsigned)u) << 16;
  return v.f;
}
__device__ inline unsigned pk2(float x, float y) {
  union { __hip_bfloat162 h; unsigned u; } c;
  c.h = __float22bfloat162_rn(float2{x, y});
  return c.u;
}
__device__ inline float fexp2(float x) {
  float r;
  asm("v_exp_f32 %0, %1" : "=v"(r) : "v"(x));
  return r;
}

__device__ inline void gload16(const void* g, void* l) {
  __builtin_amdgcn_global_load_lds(
      (const __attribute__((address_space(1))) unsigned*)g,
      (__attribute__((address_space(3))) unsigned*)l, 16, 0, 0);
}

// --- fused fp32->bf16 convert (x, w_attn, w_proj) + trig table init ---
__global__ void cvt_all(const float* __restrict__ x, const float* __restrict__ wa,
                        const float* __restrict__ wp, ushort_t* __restrict__ xb,
                        ushort_t* __restrict__ wab, ushort_t* __restrict__ wpb,
                        float* __restrict__ trig, int n8x, int n8a, int n8p) {
  int i = blockIdx.x * blockDim.x + threadIdx.x;
  const float* src; ushort_t* dst; int j;
  if (i < n8x)                  { src = x;  dst = xb;  j = i; }
  else if (i < n8x + n8a)       { src = wa; dst = wab; j = i - n8x; }
  else if (i < n8x + n8a + n8p) { src = wp; dst = wpb; j = i - n8x - n8a; }
  else {
    int idx = i - n8x - n8a - n8p;       // trig region: T*64 entries
    if (idx >= T_SEQ * 64) return;
    int fi = idx & 63, t = idx >> 6;
    float inv = __expf(-(float)fi * (9.210340371976184f / 64.0f));
    float f = (float)t * inv;
    trig[idx * 2]     = cosf(f);
    trig[idx * 2 + 1] = sinf(f);
    return;
  }
  const float4* s = (const float4*)src + (size_t)j * 2;
  float4 a = s[0], b = s[1];
  short8 o;
  o[0] = (short)f2bf(a.x); o[1] = (short)f2bf(a.y);
  o[2] = (short)f2bf(a.z); o[3] = (short)f2bf(a.w);
  o[4] = (short)f2bf(b.x); o[5] = (short)f2bf(b.y);
  o[6] = (short)f2bf(b.z); o[7] = (short)f2bf(b.w);
  *((short8*)dst + j) = o;
}

// ===== 256x128 BK=32 double-buffered GEMM, m97 regime, 0-conflict =====
// (R9-verified; R11 added fused V-transpose epilogue.)
template <int EPI>
__global__ __launch_bounds__(512, 4)
void gemm_s(const ushort_t* __restrict__ A, const ushort_t* __restrict__ Bt,
            float* __restrict__ C, ushort_t* __restrict__ q_t,
            ushort_t* __restrict__ k_t, ushort_t* __restrict__ v_t,
            const float* __restrict__ trig, int M, int N, int K) {
  __shared__ __align__(16) ushort_t sA[2][256 * 32];  // 2 x 16KB
  __shared__ __align__(16) ushort_t sB[2][128 * 32];  // 2 x 8KB
  int tid = threadIdx.x, lane = tid & 63, w = tid >> 6;
  int wm = w >> 1, wn = w & 1;
  int li = lane & 15, lg = lane >> 4;
  int tile_m = blockIdx.y * 256, tile_n = blockIdx.x * 128;
  const ushort_t* Ag = A + (size_t)tile_m * K;
  const ushort_t* Bg = Bt + (size_t)tile_n * K;

  int Rl = tid >> 3;
  int sl = tid & 7;
  int tdec = sl ^ (Rl & 7);
  int prow = (tdec >> 2) & 1, gch = tdec & 3;

  auto stage = [&](int kt, int buf) {
#pragma unroll
    for (int i = 0; i < 2; ++i) {
      int grow = (i * 64 + Rl) * 2 + prow;
      gload16(Ag + (size_t)grow * K + kt * 32 + gch * 8,
              &sA[buf][i * 4096 + tid * 8]);
    }
    {
      int grow = Rl * 2 + prow;
      gload16(Bg + (size_t)grow * K + kt * 32 + gch * 8,
              &sB[buf][tid * 8]);
    }
  };

  auto rdoff = [&](int r) {
    int R = r >> 1;
    int s = (((r & 1) << 2) | lg) ^ (R & 7);
    return R * 64 + s * 8;
  };

  f32x4 acc[4][4] = {};
  const int NT = K / 32;

  stage(0, 0);
  __syncthreads();

  for (int kt = 0; kt < NT; ++kt) {
    int cur = kt & 1;
    if (kt + 1 < NT) stage(kt + 1, cur ^ 1);
    short8 af[4], bf[4];
#pragma unroll
    for (int mi = 0; mi < 4; ++mi)
      af[mi] = *(const short8*)&sA[cur][rdoff(wm * 64 + mi * 16 + li)];
#pragma unroll
    for (int ni = 0; ni < 4; ++ni)
      bf[ni] = *(const short8*)&sB[cur][rdoff(wn * 64 + ni * 16 + li)];
    __builtin_amdgcn_s_setprio(1);
#pragma unroll
    for (int mi = 0; mi < 4; ++mi)
#pragma unroll
      for (int ni = 0; ni < 4; ++ni)
        acc[mi][ni] = __builtin_amdgcn_mfma_f32_16x16x32_bf16(af[mi], bf[ni], acc[mi][ni], 0, 0, 0);
    __builtin_amdgcn_s_setprio(0);
    __syncthreads();
  }

  if (EPI == 0) {
#pragma unroll
    for (int mi = 0; mi < 4; ++mi) {
      int trow = tile_m + wm * 64 + mi * 16 + lg * 4;
#pragma unroll
      for (int ni = 0; ni < 4; ++ni) {
        int col = tile_n + wn * 64 + ni * 16 + li;
#pragma unroll
        for (int r = 0; r < 4; ++r)
          C[(size_t)(trow + r) * N + col] = acc[mi][ni][r];
      }
    }
  } else {
    int sec = tile_n >> 11;
    int bq  = tile_m >> 11;
    int t0  = tile_m & 2047;
    int h   = (tile_n & 2047) >> 7;
    if (sec < 2) {
      ushort_t* base = ((sec == 0) ? q_t : k_t) + ((size_t)(bq * NH + h)) * T_SEQ * HD;
#pragma unroll
      for (int mi = 0; mi < 4; ++mi) {
        int tl = wm * 64 + mi * 16 + lg * 4;
#pragma unroll
        for (int ni = 0; ni < 4; ++ni) {
          int d = wn * 64 + ni * 16 + li;
          int fi2 = (d >> 1) * 2;
#pragma unroll
          for (int r = 0; r < 4; ++r) {
            int t = t0 + tl + r;
            float val = acc[mi][ni][r];
            float par = __shfl_xor(val, 1);
            const float* tp = trig + t * 128 + fi2;
            float c = tp[0], s = tp[1];
            float outv = (li & 1) ? (par * s + val * c) : (val * c - par * s);
            base[(size_t)t * HD + d] = f2bf(outv);
          }
        }
      }
    } else {
      // V: LDS-transpose 256(t) x 128(d) tile in 4 chunks of 64 t-rows.
      ushort_t* vbase = v_t + ((size_t)(bq * NH + h)) * HD * T_SEQ;
      ushort_t* L = (ushort_t*)sA;
      for (int c = 0; c < 4; ++c) {
        if (wm == c) {
#pragma unroll
          for (int mi = 0; mi < 4; ++mi) {
            int tl = mi * 16 + lg * 4;
#pragma unroll
            for (int ni = 0; ni < 4; ++ni) {
              int d = wn * 64 + ni * 16 + li;
#pragma unroll
              for (int r = 0; r < 4; ++r)
                L[d * 72 + tl + r] = f2bf(acc[mi][ni][r]);
            }
          }
        }
        __syncthreads();
#pragma unroll
        for (int j = 0; j < 2; ++j) {
          int idx = j * 512 + tid;
          int d = idx >> 3, tg = (idx & 7) * 8;
          short8 val = *(const short8*)&L[d * 72 + tg];
          *(short8*)(vbase + (size_t)d * T_SEQ + t0 + c * 64 + tg) = val;
        }
        __syncthreads();
      }
    }
  }
}

// ===== 128x128 BK=32 double-buffered GEMM (R10-proven) — for proj =====
__global__ __launch_bounds__(256, 4)
void gemm_s128(const ushort_t* __restrict__ A, const ushort_t* __restrict__ Bt,
               float* __restrict__ C, int M, int N, int K) {
  __shared__ __align__(16) ushort_t sA[2][128 * 32];
  __shared__ __align__(16) ushort_t sB[2][128 * 32];
  int tid = threadIdx.x, lane = tid & 63, w = tid >> 6;
  int wm = w >> 1, wn = w & 1;
  int li = lane & 15, lg = lane >> 4;
  int tile_m = blockIdx.y * 128, tile_n = blockIdx.x * 128;
  const ushort_t* Ag = A + (size_t)tile_m * K;
  const ushort_t* Bg = Bt + (size_t)tile_n * K;

  int Rl = tid >> 3;
  int sl = tid & 7;
  int tdec = sl ^ (Rl & 7);
  int prow = (tdec >> 2) & 1, gch = tdec & 3;

  auto stage = [&](int kt, int buf) {
#pragma unroll
    for (int i = 0; i < 2; ++i) {
      int grow = (i * 32 + Rl) * 2 + prow;
      gload16(Ag + (size_t)grow * K + kt * 32 + gch * 8,
              &sA[buf][i * 2048 + tid * 8]);
    }
#pragma unroll
    for (int i = 0; i < 2; ++i) {
      int grow = (i * 32 + Rl) * 2 + prow;
      gload16(Bg + (size_t)grow * K + kt * 32 + gch * 8,
              &sB[buf][i * 2048 + tid * 8]);
    }
  };

  auto rdoff = [&](int r) {
    int R = r >> 1;
    int s = (((r & 1) << 2) | lg) ^ (R & 7);
    return R * 64 + s * 8;
  };

  f32x4 acc[4][4] = {};
  const int NT = K / 32;

  stage(0, 0);
  __syncthreads();

  for (int kt = 0; kt < NT; ++kt) {
    int cur = kt & 1;
    if (kt + 1 < NT) stage(kt + 1, cur ^ 1);
    short8 af[4], bf[4];
#pragma unroll
    for (int mi = 0; mi < 4; ++mi)
      af[mi] = *(const short8*)&sA[cur][rdoff(wm * 64 + mi * 16 + li)];
#pragma unroll
    for (int ni = 0; ni < 4; ++ni)
      bf[ni] = *(const short8*)&sB[cur][rdoff(wn * 64 + ni * 16 + li)];
    __builtin_amdgcn_s_setprio(1);
#pragma unroll
    for (int mi = 0; mi < 4; ++mi)
#pragma unroll
      for (int ni = 0; ni < 4; ++ni)
        acc[mi][ni] = __builtin_amdgcn_mfma_f32_16x16x32_bf16(af[mi], bf[ni], acc[mi][ni], 0, 0, 0);
    __builtin_amdgcn_s_setprio(0);
    __syncthreads();
  }

#pragma unroll
  for (int mi = 0; mi < 4; ++mi) {
    int trow = tile_m + wm * 64 + mi * 16 + lg * 4;
#pragma unroll
    for (int ni = 0; ni < 4; ++ni) {
      int col = tile_n + wn * 64 + ni * 16 + li;
#pragma unroll
      for (int r = 0; r < 4; ++r)
        C[(size_t)(trow + r) * N + col] = acc[mi][ni][r];
    }
  }
}

// ---------------- Flash attention (causal), swapped-QK 32x32 ----------
// 1D grid of 512 blocks, XCD-affine decode (R12). R14: counted-vmcnt
// prefetch-depth-2 pipeline over the 2 LDS buffer sets — replaces the
// __syncthreads full-drain (which stalled ~HBM-latency every tile) with
// {barrier | stage(kt+2 -> freed buf) | vmcnt(8) | barrier}: tile kt+1's
// 8 loads get a full iteration to land; waits are counted, never 0 in
// steady state (T4). Barrier ledger: reads of buf[cur] fenced by barrier
// before its overwrite; vmcnt(8) + barrier publishes buf[cur^1] to all.
__global__ __launch_bounds__(256, 2)
void flash_attn(const ushort_t* __restrict__ Q, const ushort_t* __restrict__ Kg,
                const ushort_t* __restrict__ Vt, ushort_t* __restrict__ Y) {
  __shared__ __align__(16) ushort_t ldsK[2 * 64 * 128];   // 32KB, 2 buf
  __shared__ __align__(16) ushort_t ldsV[2 * 128 * 64];   // 32KB, 2 buf
  int tid = threadIdx.x, lane = tid & 63, w = tid >> 6;
  int hi = lane >> 5, l31 = lane & 31;
  int f = blockIdx.x;
  int xcd = f & 7, j = f >> 3;
  int bh = (xcd << 2) | (j >> 4);
  int jq = j & 15;
  int qi = (j & 32) ? (15 - jq) : jq;
  int b = bh >> 4, h = bh & 15;
  int q0 = qi * 128;
  const ushort_t* Qp = Q + (size_t)bh * T_SEQ * HD;
  const ushort_t* Kp = Kg + (size_t)bh * T_SEQ * HD;
  const ushort_t* Vp = Vt + (size_t)bh * HD * T_SEQ;

  int qg = q0 + w * 32 + l31;
  int qmaxw = q0 + w * 32 + 31;

  auto stage = [&](int kv0, int bsel) {
    ushort_t* Kb = ldsK + bsel * 8192;
    ushort_t* Vb = ldsV + bsel * 8192;
#pragma unroll
    for (int p = 0; p < 4; ++p) {
      int c = p * 256 + w * 64 + lane;
      {
        int row = c >> 4, cc = c & 15;
        int sc = cc ^ (row & 15);
        gload16(Kp + (size_t)(kv0 + row) * HD + sc * 8, Kb + (p * 256 + w * 64) * 8);
      }
      {
        int d = c >> 3, cc = c & 7;
        int sc = cc ^ (d & 7);
        gload16(Vp + (size_t)d * T_SEQ + kv0 + sc * 8, Vb + (p * 256 + w * 64) * 8);
      }
    }
  };

  short8 qf[8];
#pragma unroll
  for (int ds = 0; ds < 8; ++ds)
    qf[ds] = *(const short8*)(Qp + (size_t)qg * HD + ds * 16 + hi * 8);

  f32x16 o[4] = {};
  float mu = -1e30f, l = 0.f;
  const float SIG = 0.12751879523209784f;  // (1/sqrt(128)) * log2(e)

  int nkt = 2 * qi + 2;   // >= 2 always
  // prologue: depth-2 prefetch
  stage(0, 0);
  stage(64, 1);
  asm volatile("s_waitcnt vmcnt(8)" ::: "memory");   // tile0 landed
  __builtin_amdgcn_s_barrier();
  int cur = 0;
  for (int kt = 0; kt < nkt; ++kt) {
    int kv0 = kt * 64;
    if (kv0 <= qmaxw) {
      const ushort_t* Kb = ldsK + cur * 8192;
      const ushort_t* Vb = ldsV + cur * 8192;
      f32x16 sa = {}, sb = {};
      __builtin_amdgcn_s_setprio(1);
#pragma unroll
      for (int ds = 0; ds < 8; ++ds) {
        int cc = ds * 2 + hi;
        short8 k0 = *(const short8*)&Kb[l31 * 128 + ((cc ^ (l31 & 15)) * 8)];
        short8 k1 = *(const short8*)&Kb[(32 + l31) * 128 + ((cc ^ (l31 & 15)) * 8)];
        sa = __builtin_amdgcn_mfma_f32_32x32x16_bf16(k0, qf[ds], sa, 0, 0, 0);
        sb = __builtin_amdgcn_mfma_f32_32x32x16_bf16(k1, qf[ds], sb, 0, 0, 0);
      }
      __builtin_amdgcn_s_setprio(0);
      float p[32];
#pragma unroll
      for (int r = 0; r < 16; ++r) { p[r] = sa[r] * SIG; p[16 + r] = sb[r] * SIG; }
      if (kv0 + 63 > q0 + w * 32) {
#pragma unroll
        for (int r = 0; r < 16; ++r) {
          int loc = (r & 3) + 8 * (r >> 2) + 4 * hi;
          if (kv0 + loc > qg)      p[r]      = -3e38f;
          if (kv0 + 32 + loc > qg) p[16 + r] = -3e38f;
        }
      }
      float tm[16];
#pragma unroll
      for (int i = 0; i < 16; ++i) tm[i] = fmaxf(p[i], p[i + 16]);
#pragma unroll
      for (int st = 8; st >= 1; st >>= 1)
#pragma unroll
        for (int i = 0; i < 8; ++i)
          if (i < st) tm[i] = fmaxf(tm[i], tm[i + st]);
      float pmax = fmaxf(tm[0], __shfl_xor(tm[0], 32));
      bool resc = !__all(pmax <= mu + 11.0f);
      if (resc) {
        float munew = fmaxf(mu, pmax);
        float alpha = fexp2(mu - munew);
        mu = munew;
        l *= alpha;
#pragma unroll
        for (int dsub = 0; dsub < 4; ++dsub)
#pragma unroll
          for (int r = 0; r < 16; ++r) o[dsub][r] *= alpha;
      }
#pragma unroll
      for (int i = 0; i < 32; ++i) p[i] = fexp2(p[i] - mu);
      float ts[16];
#pragma unroll
      for (int i = 0; i < 16; ++i) ts[i] = p[i] + p[i + 16];
#pragma unroll
      for (int st = 8; st >= 1; st >>= 1)
#pragma unroll
        for (int i = 0; i < 8; ++i)
          if (i < st) ts[i] += ts[i + st];
      l += ts[0] + __shfl_xor(ts[0], 32);
      __builtin_amdgcn_s_setprio(1);
#pragma unroll
      for (int s = 0; s < 4; ++s) {
        int rb = (s >> 1) * 16 + (s & 1) * 8;
        unsigned a0 = pk2(p[rb + 0], p[rb + 1]);
        unsigned a1 = pk2(p[rb + 2], p[rb + 3]);
        unsigned a2 = pk2(p[rb + 4], p[rb + 5]);
        unsigned a3 = pk2(p[rb + 6], p[rb + 7]);
        unsigned sa0 = (unsigned)__shfl_xor((int)a0, 32);
        unsigned sa1 = (unsigned)__shfl_xor((int)a1, 32);
        unsigned sa2 = (unsigned)__shfl_xor((int)a2, 32);
        unsigned sa3 = (unsigned)__shfl_xor((int)a3, 32);
        union { unsigned u[4]; short8 s8; } pf;
        pf.u[0] = hi ? sa2 : a0;
        pf.u[1] = hi ? sa3 : a1;
        pf.u[2] = hi ? a2 : sa0;
        pf.u[3] = hi ? a3 : sa1;
#pragma unroll
        for (int dsub = 0; dsub < 4; ++dsub) {
          int row = dsub * 32 + l31;
          short8 vf = *(const short8*)&Vb[row * 64 + (((2 * s + hi) ^ (row & 7)) * 8)];
          o[dsub] = __builtin_amdgcn_mfma_f32_32x32x16_bf16(vf, pf.s8, o[dsub], 0, 0, 0);
        }
      }
      __builtin_amdgcn_s_setprio(0);
    }
    __builtin_amdgcn_s_barrier();            // all waves done reading buf[cur]
    if (kt + 2 < nkt) stage((kt + 2) * 64, cur);
    if (kt + 1 < nkt) {
      if (kt + 2 < nkt) asm volatile("s_waitcnt vmcnt(8)" ::: "memory");
      else              asm volatile("s_waitcnt vmcnt(0)" ::: "memory");
      __builtin_amdgcn_s_barrier();          // buf[cur^1] published
    }
    cur ^= 1;
  }
  float invl = 1.f / l;
#pragma unroll
  for (int dsub = 0; dsub < 4; ++dsub)
#pragma unroll
    for (int r = 0; r < 16; ++r) o[dsub][r] *= invl;
#pragma unroll
  for (int dsub = 0; dsub < 4; ++dsub)
#pragma unroll
    for (int r = 0; r < 16; r += 2) {
      int d0 = dsub * 32 + (r & 3) + 8 * (r >> 2) + 4 * hi;
      unsigned u = pk2(o[dsub][r], o[dsub][r + 1]);
      *(unsigned*)&ldsK[w * 4096 + l31 * 128 + (((d0 >> 3) ^ (l31 & 15)) * 8) + (d0 & 7)] = u;
    }
  __syncthreads();
#pragma unroll
  for (int rep = 0; rep < 8; ++rep) {
    int idx = rep * 256 + tid;
    int qg2 = idx >> 4, c = idx & 15;
    int wv2 = qg2 >> 5, ql = qg2 & 31;
    short8 val = *(const short8*)&ldsK[wv2 * 4096 + ql * 128 + ((c ^ (ql & 15)) * 8)];
    *(short8*)(Y + ((size_t)(b * T_SEQ + q0 + qg2)) * DMODEL + h * HD + c * 8) = val;
  }
}

extern "C" void kernel_launch(void* const* d_in, const int* in_sizes, int n_in,
                              void* d_out, int out_size, void* d_ws, size_t ws_size,
                              hipStream_t stream) {
  const float* x      = (const float*)d_in[0];
  const float* w_attn = (const float*)d_in[1];
  const float* w_proj = (const float*)d_in[2];
  float* out = (float*)d_out;

  char* ws = (char*)d_ws;
  size_t off = 0;
  auto alloc = [&](size_t bytes) -> void* {
    void* p = ws + off;
    off = (off + bytes + 255) & ~(size_t)255;
    return p;
  };
  const size_t MT = (size_t)NB * T_SEQ;          // 4096
  ushort_t* xb   = (ushort_t*)alloc(MT * DMODEL * 2);
  ushort_t* wab  = (ushort_t*)alloc((size_t)3 * DMODEL * DMODEL * 2);
  ushort_t* wpb  = (ushort_t*)alloc((size_t)DMODEL * DMODEL * 2);
  ushort_t* q_t  = (ushort_t*)alloc(MT * DMODEL * 2);
  ushort_t* k_t  = (ushort_t*)alloc(MT * DMODEL * 2);
  ushort_t* vtb  = (ushort_t*)alloc(MT * DMODEL * 2);
  ushort_t* yb   = (ushort_t*)alloc(MT * DMODEL * 2);
  float*    trig = (float*)alloc((size_t)T_SEQ * 64 * 2 * 4);
  (void)ws_size; (void)n_in; (void)in_sizes; (void)out_size;

  {  // one fused convert + trig launch
    int n8x = (int)(MT * DMODEL / 8);
    int n8a = (int)((size_t)3 * DMODEL * DMODEL / 8);
    int n8p = (int)((size_t)DMODEL * DMODEL / 8);
    int tot = n8x + n8a + n8p + T_SEQ * 64;
    hipLaunchKernelGGL(cvt_all, dim3((tot + 255) / 256), dim3(256), 0, stream,
                       x, w_attn, w_proj, xb, wab, wpb, trig, n8x, n8a, n8p);
  }

  // QKV projection (256x128 R9 config): rope-fused q/k, LDS-transposed v
  hipLaunchKernelGGL((gemm_s<1>), dim3(3 * DMODEL / 128, MT / 256), dim3(512), 0, stream,
                     xb, wab, (float*)nullptr, q_t, k_t, vtb, trig,
                     (int)MT, 3 * DMODEL, DMODEL);

  // flash attention: 1D grid, XCD-affine head placement, counted-vmcnt pipe
  hipLaunchKernelGGL(flash_attn, dim3(512), dim3(256), 0, stream,
                     q_t, k_t, vtb, yb);

  // output projection: 128^2 tile -> 512 blocks = 2/CU
  hipLaunchKernelGGL(gemm_s128, dim3(DMODEL / 128, MT / 128), dim3(256), 0, stream,
                     yb, wpb, out, (int)MT, DMODEL, DMODEL);
}